// Round 15
// baseline (188.505 us; speedup 1.0000x reference)
//
#include <hip/hip_runtime.h>

#define NTOT 8192
#define CDIM 512
#define KCL 27

typedef __attribute__((ext_vector_type(8))) short short8;
typedef __attribute__((ext_vector_type(4))) float f32x4;

static __device__ __forceinline__ unsigned short f2bf(float v) {
  union { float f; unsigned u; } z; z.f = v;
  unsigned r = (z.u + 0x7FFFu + ((z.u >> 16) & 1u)) >> 16;
  return (unsigned short)r;
}

static __device__ __forceinline__ void gld16(const unsigned short* g, char* l) {
  __builtin_amdgcn_global_load_lds(
      (const __attribute__((address_space(1))) void*)g,
      (__attribute__((address_space(3))) void*)l, 16, 0, 0);
}

// ---------------- K1: normalize clusters -> nclb bf16 [32][512] ----------------
__global__ void k_clusters(const float* __restrict__ cl, unsigned short* __restrict__ nclb) {
  int k = blockIdx.x;
  int t = threadIdx.x; // 64
  const float* row = cl + (size_t)k * CDIM;
  float ss = 0.f;
  for (int c = t; c < CDIM; c += 64) { float v = row[c]; ss += v * v; }
  for (int o = 32; o; o >>= 1) ss += __shfl_down(ss, o);
  ss = __shfl(ss, 0);
  float inv = 1.f / fmaxf(sqrtf(ss), 1e-12f);
  for (int c = t; c < CDIM; c += 64) nclb[(size_t)k * CDIM + c] = f2bf(row[c] * inv);
}

// ---------------- K2: permute(0,3,2,1) -> mbf bf16 [N][C] (UNNORMALIZED) + sq-partials ----------------
// 512 blocks (bh, cq); x read ONCE. sqpart[cq][bh*64+w] = sum over c-slice of x^2 for pixel (w,h).
__global__ __launch_bounds__(256) void k_merged2(const float* __restrict__ x,
    unsigned short* __restrict__ mbf, float* __restrict__ sqpart) {
  __shared__ float tile[64][65];
  __shared__ float part[4][64];
  int bid = blockIdx.x;
  int bh = bid >> 2, cq = bid & 3;
  int b = bh >> 6, h = bh & 63;
  int t = threadIdx.x;
  int w = t & 63, cg = t >> 6;
  const float* xb = x + (size_t)b * CDIM * 4096 + (size_t)h * 64; // xb[c*4096 + w]
  float ss = 0.f;
  for (int c0 = cq * 128; c0 < cq * 128 + 128; c0 += 64) {
#pragma unroll
    for (int q = 0; q < 16; ++q) {
      int c = cg + q * 4;
      float v = xb[(size_t)(c0 + c) * 4096 + w];
      tile[c][w] = v;
      ss += v * v;                       // partial for pixel n = b*4096 + w*64 + h
    }
    __syncthreads();
#pragma unroll
    for (int q = 0; q < 16; ++q) {
      int ww = cg + q * 4;
      int n = b * 4096 + ww * 64 + h;    // n from permute(0,3,2,1)
      mbf[(size_t)n * CDIM + c0 + w] = f2bf(tile[w][ww]);
    }
    __syncthreads();
  }
  part[cg][w] = ss;
  __syncthreads();
  if (t < 64) {
    float s = part[0][t] + part[1][t] + part[2][t] + part[3][t];
    sqpart[(size_t)cq * NTOT + bh * 64 + t] = s;   // coalesced 256B
  }
}

// ---------------- K3 (MFMA): inner = mbf @ nclb^T scaled by inv_n; writes invn for k_fused ----------------
__global__ __launch_bounds__(256) void k_inner2(const unsigned short* __restrict__ mbf,
    const unsigned short* __restrict__ nclb, const float* __restrict__ alpha_p,
    const float* __restrict__ sqpart, float* __restrict__ invn,
    float* __restrict__ sT, float* __restrict__ maxv,
    float* __restrict__ out_cp, unsigned short* __restrict__ sxbf) {
  __shared__ float red[4][32][33];
  __shared__ float innerS[32][33];
  __shared__ float rowml[32], rowls[32], rowsum[32], rowivn[32];
  int t = threadIdx.x;
  int wv = t >> 6, lane = t & 63;
  int r15 = lane & 15, kgrp = lane >> 4;
  int I0 = blockIdx.x * 32;
  float alpha = alpha_p[0];

  if (t < 32) {                          // per-row inverse norm from sq-partials
    int n = I0 + t;
    int b = n >> 12, w = (n >> 6) & 63, h = n & 63;
    int idx = (b * 64 + h) * 64 + w;
    float s = sqpart[idx] + sqpart[NTOT + idx] + sqpart[2 * NTOT + idx] + sqpart[3 * NTOT + idx];
    float iv = 1.f / fmaxf(sqrtf(s), 1e-12f);
    rowivn[t] = iv;
    invn[n] = iv;
  }

  f32x4 acc[2][2];
#pragma unroll
  for (int m = 0; m < 2; ++m)
#pragma unroll
    for (int n = 0; n < 2; ++n) acc[m][n] = (f32x4){0.f, 0.f, 0.f, 0.f};

#pragma unroll
  for (int ks = 0; ks < 4; ++ks) {
    int kbase = wv * 128 + ks * 32 + kgrp * 8;
    short8 a[2], b[2];
#pragma unroll
    for (int m = 0; m < 2; ++m)
      a[m] = *(const short8*)(mbf + (size_t)(I0 + m * 16 + r15) * CDIM + kbase);
#pragma unroll
    for (int n = 0; n < 2; ++n)
      b[n] = *(const short8*)(nclb + (size_t)(n * 16 + r15) * CDIM + kbase);
#pragma unroll
    for (int m = 0; m < 2; ++m)
#pragma unroll
      for (int n = 0; n < 2; ++n)
        acc[m][n] = __builtin_amdgcn_mfma_f32_16x16x32_bf16(a[m], b[n], acc[m][n], 0, 0, 0);
  }
#pragma unroll
  for (int m = 0; m < 2; ++m)
#pragma unroll
    for (int n = 0; n < 2; ++n)
#pragma unroll
      for (int reg = 0; reg < 4; ++reg)
        red[wv][m * 16 + kgrp * 4 + reg][n * 16 + r15] = acc[m][n][reg];
  __syncthreads();
  for (int idx = t; idx < 1024; idx += 256) {
    int r = idx >> 5, c = idx & 31;
    innerS[r][c] = red[0][r][c] + red[1][r][c] + red[2][r][c] + red[3][r][c];
  }
  __syncthreads();
  if (t < 32) {
    float ivn = rowivn[t];
    float mi = -3.4e38f, ml = -3.4e38f;
    for (int k = 0; k < KCL; ++k) {
      float iv = innerS[t][k] * ivn;     // scaled inner
      mi = fmaxf(mi, iv);
      ml = fmaxf(ml, alpha * iv);
    }
    float sum = 0.f;
    for (int k = 0; k < KCL; ++k) sum += expf(alpha * innerS[t][k] * ivn - ml);
    rowml[t] = ml;
    rowls[t] = ml + logf(sum);
    rowsum[t] = 1.f / sum;
    maxv[I0 + t] = mi;
    sxbf[I0 + t] = 0x3F80;               // Sx row 0 = 1.0
  }
  __syncthreads();
  for (int idx = t; idx < 32 * KCL; idx += 256) {
    int r = idx / KCL, k = idx - r * KCL;
    int n = I0 + r;
    float iv = innerS[r][k] * rowivn[r];
    float sv = expf(alpha * iv - rowml[r]) * rowsum[r];
    sT[(size_t)k * NTOT + n] = sv;
    sxbf[(size_t)(k + 1) * NTOT + n] = f2bf(sv);
    int b = n >> 12, w = (n >> 6) & 63, h = n & 63;
    out_cp[(((size_t)b * KCL + k) * 64 + h) * 64 + w] = alpha * iv - rowls[r];
  }
}

// ---------------- K4 (fused): Rpart[jc][28][N] = relu((X X^T)*inv_i*inv_j, diag=0) @ [1|S] ----------------
// Round-12 structure: counted vmcnt(4), 2-deep 2-buffer, async pre-swizzled Sx,
// Prow aliases staging (LDS 40960). QK on UNNORMALIZED mbf; scale in epilogue.
__global__ __launch_bounds__(256) void k_fused(const unsigned short* __restrict__ Mb,
    const unsigned short* __restrict__ sxT, const float* __restrict__ invn,
    float* __restrict__ Rpart) {
  __shared__ char lds[40960];
  char* bufJ0 = lds;            // [0,8K)
  char* bufI0 = lds + 8192;     // [8K,16K)
  char* bufJ1 = lds + 16384;    // [16K,24K)
  char* bufI1 = lds + 24576;    // [24K,32K)
  char* Prow  = lds;            // [0,32K) aliases all staging buffers
  char* Sx    = lds + 32768;    // [32K,40K)
  int t = threadIdx.x;
  int wid = t >> 6, lane = t & 63;
  int r15 = lane & 15, kgrp = lane >> 4;
  int wrj = wid >> 1, wci = wid & 1;
  int I0 = blockIdx.x * 128;
  int Jbase = blockIdx.y * 512;

  f32x4 pv[2][2];
#pragma unroll
  for (int m = 0; m < 2; ++m)
#pragma unroll
    for (int n = 0; n < 2; ++n) pv[m][n] = (f32x4){0.f, 0.f, 0.f, 0.f};

  // QK staging: linear LDS dest; pre-swizzled global source col (slot ^ (row&3)).
  int srow = wid * 16 + (lane >> 2);
  int scol = (((lane & 3) ^ ((lane >> 2) & 3)) * 8);   // elements
  int ldst = wid * 1024;
  const unsigned short* gI0 = Mb + (size_t)(I0 + srow) * CDIM + scol;
  const unsigned short* gI1 = Mb + (size_t)(I0 + 64 + srow) * CDIM + scol;

  // per-lane inv_i for the 4 i-frag positions (loop-invariant)
  float invI[4];
#pragma unroll
  for (int n = 0; n < 4; ++n) invI[n] = invn[I0 + wci * 64 + n * 16 + r15];

  // Sx staging geometry
  int sx_c_local = wid * 4 + (lane >> 4);
  int sx_slot = lane & 15;

  for (int jt = 0; jt < 4; ++jt) {
    int J0 = Jbase + jt * 128;
    const unsigned short* gJ0 = Mb + (size_t)(J0 + srow) * CDIM + scol;
    const unsigned short* gJ1 = Mb + (size_t)(J0 + 64 + srow) * CDIM + scol;

    __syncthreads();   // prev jt's PV readers done before Sx/staging overwrite

    // Sx tile [32 c][128 j] via async gld16, source pre-swizzled
#pragma unroll
    for (int r2 = 0; r2 < 2; ++r2) {
      int c = r2 * 16 + sx_c_local;
      int j = ((sx_slot ^ (c & 15)) * 8);
      gld16(sxT + (size_t)c * NTOT + J0 + j, Sx + (r2 * 16 + wid * 4) * 256);
    }

#define ISSUE(KS, BJ, BI)                                                      \
    { gld16(gJ0 + (KS) * 32, (BJ) + ldst);                                     \
      gld16(gJ1 + (KS) * 32, (BJ) + 4096 + ldst);                              \
      gld16(gI0 + (KS) * 32, (BI) + ldst);                                     \
      gld16(gI1 + (KS) * 32, (BI) + 4096 + ldst); }

#define QKSTEP(BJ, BI)                                                         \
    {                                                                          \
      short8 a[4], b[4];                                                       \
      _Pragma("unroll")                                                        \
      for (int m = 0; m < 4; ++m)                                              \
        a[m] = *(const short8*)((BJ) + ((wrj * 64 + m * 16 + r15) * 64 +       \
                                        ((kgrp * 16) ^ ((r15 & 3) << 4))));    \
      _Pragma("unroll")                                                        \
      for (int n = 0; n < 4; ++n)                                              \
        b[n] = *(const short8*)((BI) + ((wci * 64 + n * 16 + r15) * 64 +       \
                                        ((kgrp * 16) ^ ((r15 & 3) << 4))));    \
      _Pragma("unroll")                                                        \
      for (int m = 0; m < 4; ++m)                                              \
        _Pragma("unroll")                                                      \
        for (int n = 0; n < 4; ++n)                                            \
          acc[m][n] = __builtin_amdgcn_mfma_f32_16x16x32_bf16(a[m], b[n], acc[m][n], 0, 0, 0); \
    }

    // prologue: Sx (2) + 2-deep QK prefetch (8) outstanding
    ISSUE(0, bufJ0, bufI0);
    ISSUE(1, bufJ1, bufI1);

    f32x4 acc[4][4];
#pragma unroll
    for (int m = 0; m < 4; ++m)
#pragma unroll
      for (int n = 0; n < 4; ++n) acc[m][n] = (f32x4){0.f, 0.f, 0.f, 0.f};

    // steady state: wait only for loads issued 2 K-steps ago
#pragma unroll 1
    for (int kk = 0; kk < 14; kk += 2) {
      asm volatile("s_waitcnt vmcnt(4)" ::: "memory");
      __builtin_amdgcn_s_barrier();
      __builtin_amdgcn_sched_barrier(0);
      QKSTEP(bufJ0, bufI0);
      __builtin_amdgcn_sched_barrier(0);
      __builtin_amdgcn_s_barrier();
      ISSUE(kk + 2, bufJ0, bufI0);
      asm volatile("s_waitcnt vmcnt(4)" ::: "memory");
      __builtin_amdgcn_s_barrier();
      __builtin_amdgcn_sched_barrier(0);
      QKSTEP(bufJ1, bufI1);
      __builtin_amdgcn_sched_barrier(0);
      __builtin_amdgcn_s_barrier();
      ISSUE(kk + 3, bufJ1, bufI1);
    }
    // epilogue K-steps 14,15
    asm volatile("s_waitcnt vmcnt(4)" ::: "memory");
    __builtin_amdgcn_s_barrier();
    __builtin_amdgcn_sched_barrier(0);
    QKSTEP(bufJ0, bufI0);
    __builtin_amdgcn_sched_barrier(0);
    __builtin_amdgcn_s_barrier();
    asm volatile("s_waitcnt vmcnt(0)" ::: "memory");
    __builtin_amdgcn_s_barrier();
    __builtin_amdgcn_sched_barrier(0);
    QKSTEP(bufJ1, bufI1);
    __builtin_amdgcn_sched_barrier(0);
    __builtin_amdgcn_s_barrier();   // all QK reads done -> Prow may overwrite bufs
#undef QKSTEP
#undef ISSUE

    // acc = raw X X^T tile (P^T layout): row j = wrj*64+m*16+kgrp*4+reg,
    // col i = wci*64+n*16+r15. Scale by inv_i*inv_j, relu, diag, pack bf16.
#pragma unroll
    for (int m = 0; m < 4; ++m) {
      f32x4 ivJ = *(const f32x4*)&invn[J0 + wrj * 64 + m * 16 + kgrp * 4];
#pragma unroll
      for (int n = 0; n < 4; ++n) {
        int iloc = wci * 64 + n * 16 + r15;
        int gi = I0 + iloc;
        int jloc = wrj * 64 + m * 16 + kgrp * 4;
        int gj = J0 + jloc;
        unsigned short h[4];
#pragma unroll
        for (int reg = 0; reg < 4; ++reg) {
          float v = acc[m][n][reg] * invI[n] * ivJ[reg];
          v = v > 0.f ? v : 0.f;
          if (gj + reg == gi) v = 0.f;
          h[reg] = f2bf(v);
        }
        uint2 pk;
        pk.x = (unsigned)h[0] | ((unsigned)h[1] << 16);
        pk.y = (unsigned)h[2] | ((unsigned)h[3] << 16);
        *(uint2*)(Prow + iloc * 256 + ((jloc * 2) ^ ((iloc & 15) << 4))) = pk;
      }
    }
    __syncthreads();

    // PV: pv += Ptile(128x128) @ Sx(128x32); wave owns rows wid*32..+32
#pragma unroll
    for (int ks = 0; ks < 4; ++ks) {
      short8 a2[2], b2[2];
#pragma unroll
      for (int m2 = 0; m2 < 2; ++m2) {
        int iloc = wid * 32 + m2 * 16 + r15;
        a2[m2] = *(const short8*)(Prow + iloc * 256 +
                                  ((ks * 64 + kgrp * 16) ^ ((iloc & 15) << 4)));
      }
#pragma unroll
      for (int n2 = 0; n2 < 2; ++n2) {
        int c = n2 * 16 + r15;
        b2[n2] = *(const short8*)(Sx + c * 256 +
                                  ((ks * 64 + kgrp * 16) ^ ((c & 15) << 4)));
      }
#pragma unroll
      for (int m2 = 0; m2 < 2; ++m2)
#pragma unroll
        for (int n2 = 0; n2 < 2; ++n2)
          pv[m2][n2] = __builtin_amdgcn_mfma_f32_16x16x32_bf16(a2[m2], b2[n2], pv[m2][n2], 0, 0, 0);
    }
  }

  // write transposed Rpart[jc][c][gi]: 4 consecutive gi per lane -> float4 store
#pragma unroll
  for (int m2 = 0; m2 < 2; ++m2) {
#pragma unroll
    for (int n2 = 0; n2 < 2; ++n2) {
      int c = n2 * 16 + r15;
      if (c < 28) {
        int gi = I0 + wid * 32 + m2 * 16 + kgrp * 4;
        *(f32x4*)(&Rpart[((size_t)blockIdx.y * 28 + c) * NTOT + gi]) = pv[m2][n2];
      }
    }
  }
}

// ---------------- K6 (MFMA syrk): Gpart[kb][32][32] = Sx(:, kb-chunk) Sx^T ----------------
__global__ __launch_bounds__(256) void k_sts2(const unsigned short* __restrict__ sxbf,
    float* __restrict__ Gpart) {
  __shared__ float red[4][32][33];
  int t = threadIdx.x;
  int wv = t >> 6, lane = t & 63;
  int r15 = lane & 15, kgrp = lane >> 4;
  int kbase = blockIdx.x * 128 + wv * 32 + kgrp * 8;
  short8 a[2];
#pragma unroll
  for (int m = 0; m < 2; ++m)
    a[m] = *(const short8*)(sxbf + (size_t)(m * 16 + r15) * NTOT + kbase);
  f32x4 g4[2][2];
#pragma unroll
  for (int m = 0; m < 2; ++m)
#pragma unroll
    for (int n = 0; n < 2; ++n) {
      g4[m][n] = (f32x4){0.f, 0.f, 0.f, 0.f};
      g4[m][n] = __builtin_amdgcn_mfma_f32_16x16x32_bf16(a[m], a[n], g4[m][n], 0, 0, 0);
    }
#pragma unroll
  for (int m = 0; m < 2; ++m)
#pragma unroll
    for (int n = 0; n < 2; ++n)
#pragma unroll
      for (int reg = 0; reg < 4; ++reg)
        red[wv][m * 16 + kgrp * 4 + reg][n * 16 + r15] = g4[m][n][reg];
  __syncthreads();
  for (int idx = t; idx < 1024; idx += 256) {
    int r = idx >> 5, c = idx & 31;
    Gpart[(size_t)blockIdx.x * 1024 + idx] = red[0][r][c] + red[1][r][c] + red[2][r][c] + red[3][r][c];
  }
}

// ---------------- K7a: grid-parallel reduction of Rpart -> 128x30 partials ----------------
__global__ __launch_bounds__(64) void k_reduce1(const float* __restrict__ Rpart,
    const float* __restrict__ sT, const float* __restrict__ maxv,
    float* __restrict__ partials) {
  int t = threadIdx.x;
  int n = blockIdx.x * 64 + t;
  float rsum[28];
#pragma unroll
  for (int c = 0; c < 28; ++c) rsum[c] = 0.f;
#pragma unroll
  for (int bs = 0; bs < 16; ++bs)
#pragma unroll
    for (int c = 0; c < 28; ++c)
      rsum[c] += Rpart[((size_t)bs * 28 + c) * NTOT + n];
  float deg = rsum[0];
  float T1 = 0.f;
  float vloc[KCL];
#pragma unroll
  for (int k = 0; k < KCL; ++k) {
    float sv = sT[(size_t)k * NTOT + n];
    T1 += sv * rsum[1 + k];
    vloc[k] = deg * sv;
  }
  float mx = maxv[n];
  for (int o = 32; o; o >>= 1) {
    deg += __shfl_down(deg, o);
    T1 += __shfl_down(T1, o);
    mx += __shfl_down(mx, o);
  }
#pragma unroll
  for (int k = 0; k < KCL; ++k)
    for (int o = 32; o; o >>= 1) vloc[k] += __shfl_down(vloc[k], o);
  if (t == 0) {
    float* p = partials + blockIdx.x * 30;
    p[0] = deg; p[1] = T1; p[2] = mx;
#pragma unroll
    for (int k = 0; k < KCL; ++k) p[3 + k] = vloc[k];
  }
}

// ---------------- K7b: tiny final combine + ortho ----------------
__device__ float block_sum_1024(float v) {
  __shared__ float sc[16];
  for (int o = 32; o; o >>= 1) v += __shfl_down(v, o);
  __syncthreads();
  if ((threadIdx.x & 63) == 0) sc[threadIdx.x >> 6] = v;
  __syncthreads();
  if (threadIdx.x == 0) {
    float r = 0.f;
    for (int i = 0; i < 16; ++i) r += sc[i];
    sc[0] = r;
  }
  __syncthreads();
  return sc[0];
}

__global__ __launch_bounds__(1024) void k_final2(const float* __restrict__ partials,
    const float* __restrict__ Gpart, float* __restrict__ out) {
  __shared__ float comb[30];
  int t = threadIdx.x;
  if (t < 30) {
    float a = 0.f;
    for (int b = 0; b < 128; ++b) a += partials[b * 30 + t];
    comb[t] = a;
  }
  float val = 0.f;
  if (t < 729) {
    int k = t / 27, l = t - k * 27;
    int gidx = (k + 1) * 32 + (l + 1);
    for (int b = 0; b < 64; ++b) val += Gpart[(size_t)b * 1024 + gidx];
  }
  __syncthreads();
  float F2 = block_sum_1024(val * val);
  float F = sqrtf(F2);
  bool diag = (t < 729) && (t % 28 == 0);
  float gg = (t < 729) ? (val / F - (diag ? (1.f / sqrtf(27.f)) : 0.f)) : 0.f;
  float O2 = block_sum_1024(gg * gg);
  float ortho = sqrtf(O2);
  if (t == 0) {
    float sumDeg = comb[0], T1 = comb[1], maxsum = comb[2];
    float norm = 0.5f * sumDeg;
    float vv = 0.f;
    for (int k = 0; k < KCL; ++k) vv += comb[3 + k] * comb[3 + k];
    float c = 0.05f / (2.f * norm);
    float sm = -(T1 - c * vv) / (2.f * norm);
    float cl = -maxsum / (float)NTOT;
    out[0] = sm + cl + ortho;
    out[1] = sm;
  }
}

extern "C" void kernel_launch(void* const* d_in, const int* in_sizes, int n_in,
                              void* d_out, int out_size, void* d_ws, size_t ws_size,
                              hipStream_t stream) {
  const float* x        = (const float*)d_in[0];
  const float* clusters = (const float*)d_in[1];
  const float* alpha    = (const float*)d_in[2];
  float* out = (float*)d_out;
  float* ws  = (float*)d_ws;

  // workspace layout (float offsets)
  const size_t OFF_MBF  = 0;                                    // bf16 [8192][512]
  const size_t OFF_NCLB = (size_t)NTOT * CDIM / 2;              // bf16 [32][512]
  const size_t OFF_ST   = OFF_NCLB + (size_t)32 * CDIM / 2;     // f32 sT [27][8192]
  const size_t OFF_SXB  = OFF_ST + (size_t)NTOT * KCL;          // bf16 sxT [32][8192]
  const size_t OFF_MAXV = OFF_SXB + (size_t)32 * NTOT / 2;
  const size_t OFF_INVN = OFF_MAXV + NTOT;                      // f32 [8192]
  const size_t OFF_SQ   = OFF_INVN + NTOT;                      // f32 [4][8192]
  const size_t OFF_R    = OFF_SQ + (size_t)4 * NTOT;            // Rpart: 16*28*8192 f32
  const size_t OFF_GP   = OFF_R + (size_t)16 * 28 * NTOT;       // Gpart: 64*1024 f32
  const size_t OFF_PART = OFF_GP + (size_t)64 * 1024;           // 128*30 partials

  unsigned short* mbf  = (unsigned short*)(ws + OFF_MBF);
  unsigned short* nclb = (unsigned short*)(ws + OFF_NCLB);
  unsigned short* sxbf = (unsigned short*)(ws + OFF_SXB);

  // no memsets needed: nclb rows 27-31 / sxbf rows 28-31 feed only output
  // columns >= 28, which are never read (PV write guarded c<28; k_final2
  // reads Gpart indices 1..27 only). Contents are replay-invariant.
  k_clusters<<<27, 64, 0, stream>>>(clusters, nclb);
  k_merged2<<<512, 256, 0, stream>>>(x, mbf, ws + OFF_SQ);
  k_inner2<<<256, 256, 0, stream>>>(mbf, nclb, alpha, ws + OFF_SQ, ws + OFF_INVN,
                                    ws + OFF_ST, ws + OFF_MAXV, out + 2, sxbf);
  k_fused<<<dim3(64, 16), 256, 0, stream>>>(mbf, sxbf, ws + OFF_INVN, ws + OFF_R);
  k_sts2<<<64, 256, 0, stream>>>(sxbf, ws + OFF_GP);
  k_reduce1<<<128, 64, 0, stream>>>(ws + OFF_R, ws + OFF_ST, ws + OFF_MAXV,
                                    ws + OFF_PART);
  k_final2<<<1, 1024, 0, stream>>>(ws + OFF_PART, ws + OFF_GP, out);
}

// Round 16
// 144.020 us; speedup vs baseline: 1.3089x; 1.3089x over previous
//
#include <hip/hip_runtime.h>

#define NTOT 8192
#define CDIM 512
#define KCL 27

typedef __attribute__((ext_vector_type(8))) short short8;
typedef __attribute__((ext_vector_type(4))) float f32x4;

static __device__ __forceinline__ unsigned short f2bf(float v) {
  union { float f; unsigned u; } z; z.f = v;
  unsigned r = (z.u + 0x7FFFu + ((z.u >> 16) & 1u)) >> 16;
  return (unsigned short)r;
}

static __device__ __forceinline__ float bf2f(unsigned short h) {
  union { unsigned u; float f; } z; z.u = ((unsigned)h) << 16;
  return z.f;
}

static __device__ __forceinline__ void gld16(const unsigned short* g, char* l) {
  __builtin_amdgcn_global_load_lds(
      (const __attribute__((address_space(1))) void*)g,
      (__attribute__((address_space(3))) void*)l, 16, 0, 0);
}

// ---------------- K1: normalize clusters -> nclb bf16 [32][512] ----------------
__global__ void k_clusters(const float* __restrict__ cl, unsigned short* __restrict__ nclb) {
  int k = blockIdx.x;
  int t = threadIdx.x; // 64
  const float* row = cl + (size_t)k * CDIM;
  float ss = 0.f;
  for (int c = t; c < CDIM; c += 64) { float v = row[c]; ss += v * v; }
  for (int o = 32; o; o >>= 1) ss += __shfl_down(ss, o);
  ss = __shfl(ss, 0);
  float inv = 1.f / fmaxf(sqrtf(ss), 1e-12f);
  for (int c = t; c < CDIM; c += 64) nclb[(size_t)k * CDIM + c] = f2bf(row[c] * inv);
}

// ---------------- K2: permute(0,3,2,1) -> mbf bf16 [N][C] (UNNORMALIZED) + sq-partials ----------------
// 512 blocks (bh, cq); x read ONCE. sqpart[cq][bh*64+w] = sum over c-slice of x^2 for pixel n=b*4096+w*64+h.
__global__ __launch_bounds__(256) void k_merged2(const float* __restrict__ x,
    unsigned short* __restrict__ mbf, float* __restrict__ sqpart) {
  __shared__ float tile[64][65];
  __shared__ float part[4][64];
  int bid = blockIdx.x;
  int bh = bid >> 2, cq = bid & 3;
  int b = bh >> 6, h = bh & 63;
  int t = threadIdx.x;
  int w = t & 63, cg = t >> 6;
  const float* xb = x + (size_t)b * CDIM * 4096 + (size_t)h * 64; // xb[c*4096 + w]
  float ss = 0.f;
  for (int c0 = cq * 128; c0 < cq * 128 + 128; c0 += 64) {
#pragma unroll
    for (int q = 0; q < 16; ++q) {
      int c = cg + q * 4;
      float v = xb[(size_t)(c0 + c) * 4096 + w];
      tile[c][w] = v;
      ss += v * v;
    }
    __syncthreads();
#pragma unroll
    for (int q = 0; q < 16; ++q) {
      int ww = cg + q * 4;
      int n = b * 4096 + ww * 64 + h;    // n from permute(0,3,2,1)
      mbf[(size_t)n * CDIM + c0 + w] = f2bf(tile[w][ww]);
    }
    __syncthreads();
  }
  part[cg][w] = ss;
  __syncthreads();
  if (t < 64) {
    float s = part[0][t] + part[1][t] + part[2][t] + part[3][t];
    sqpart[(size_t)cq * NTOT + bh * 64 + t] = s;   // coalesced
  }
}

// ---------------- K2c: scale mbf rows in place by inverse norm (from sq-partials) ----------------
// 2048 blocks x 256 threads; thread handles 8 bf16 of row n = gid/64 (wave = one row).
__global__ __launch_bounds__(256) void k_scale(const float* __restrict__ sqpart,
    unsigned short* __restrict__ mbf) {
  int gid = blockIdx.x * 256 + threadIdx.x;
  int n = gid >> 6;
  int c8 = (gid & 63) * 8;
  int b = n >> 12, w = (n >> 6) & 63, h = n & 63;
  int idx = (b * 64 + h) * 64 + w;
  float s = sqpart[idx] + sqpart[NTOT + idx] + sqpart[2 * NTOT + idx] + sqpart[3 * NTOT + idx];
  float inv = 1.f / fmaxf(sqrtf(s), 1e-12f);
  unsigned short* p = mbf + (size_t)n * CDIM + c8;
  short8 v = *(short8*)p;
  short8 o;
#pragma unroll
  for (int i = 0; i < 8; ++i)
    o[i] = (short)f2bf(bf2f((unsigned short)v[i]) * inv);
  *(short8*)p = o;
}

// ---------------- K3 (MFMA): inner = mbf @ nclb^T; softmax/log_softmax/max; sT, sxbf, out_cp, maxv ----------------
__global__ __launch_bounds__(256) void k_inner2(const unsigned short* __restrict__ mbf,
    const unsigned short* __restrict__ nclb, const float* __restrict__ alpha_p,
    float* __restrict__ sT, float* __restrict__ maxv,
    float* __restrict__ out_cp, unsigned short* __restrict__ sxbf) {
  __shared__ float red[4][32][33];
  __shared__ float innerS[32][33];
  __shared__ float rowml[32], rowls[32], rowinv[32];
  int t = threadIdx.x;
  int wv = t >> 6, lane = t & 63;
  int r15 = lane & 15, kgrp = lane >> 4;
  int I0 = blockIdx.x * 32;
  float alpha = alpha_p[0];

  f32x4 acc[2][2];
#pragma unroll
  for (int m = 0; m < 2; ++m)
#pragma unroll
    for (int n = 0; n < 2; ++n) acc[m][n] = (f32x4){0.f, 0.f, 0.f, 0.f};

#pragma unroll
  for (int ks = 0; ks < 4; ++ks) {
    int kbase = wv * 128 + ks * 32 + kgrp * 8;
    short8 a[2], b[2];
#pragma unroll
    for (int m = 0; m < 2; ++m)
      a[m] = *(const short8*)(mbf + (size_t)(I0 + m * 16 + r15) * CDIM + kbase);
#pragma unroll
    for (int n = 0; n < 2; ++n)
      b[n] = *(const short8*)(nclb + (size_t)(n * 16 + r15) * CDIM + kbase);
#pragma unroll
    for (int m = 0; m < 2; ++m)
#pragma unroll
      for (int n = 0; n < 2; ++n)
        acc[m][n] = __builtin_amdgcn_mfma_f32_16x16x32_bf16(a[m], b[n], acc[m][n], 0, 0, 0);
  }
#pragma unroll
  for (int m = 0; m < 2; ++m)
#pragma unroll
    for (int n = 0; n < 2; ++n)
#pragma unroll
      for (int reg = 0; reg < 4; ++reg)
        red[wv][m * 16 + kgrp * 4 + reg][n * 16 + r15] = acc[m][n][reg];
  __syncthreads();
  for (int idx = t; idx < 1024; idx += 256) {
    int r = idx >> 5, c = idx & 31;
    innerS[r][c] = red[0][r][c] + red[1][r][c] + red[2][r][c] + red[3][r][c];
  }
  __syncthreads();
  if (t < 32) {
    float mi = -3.4e38f, ml = -3.4e38f;
    for (int k = 0; k < KCL; ++k) {
      float iv = innerS[t][k];
      mi = fmaxf(mi, iv);
      ml = fmaxf(ml, alpha * iv);
    }
    float sum = 0.f;
    for (int k = 0; k < KCL; ++k) sum += expf(alpha * innerS[t][k] - ml);
    rowml[t] = ml;
    rowls[t] = ml + logf(sum);
    rowinv[t] = 1.f / sum;
    maxv[I0 + t] = mi;
    sxbf[I0 + t] = 0x3F80;                     // Sx row 0 = 1.0
  }
  __syncthreads();
  for (int idx = t; idx < 32 * KCL; idx += 256) {
    int r = idx / KCL, k = idx - r * KCL;
    int n = I0 + r;
    float iv = innerS[r][k];
    float sv = expf(alpha * iv - rowml[r]) * rowinv[r];
    sT[(size_t)k * NTOT + n] = sv;
    sxbf[(size_t)(k + 1) * NTOT + n] = f2bf(sv);
    int b = n >> 12, w = (n >> 6) & 63, h = n & 63;
    out_cp[(((size_t)b * KCL + k) * 64 + h) * 64 + w] = alpha * iv - rowls[r];
  }
}

// ---------------- K4 (fused): Rpart[jc][28][N] = relu(Mi Mj^T, diag=0) @ [1|S] ----------------
// Round-12/14 version (best validated, VGPR 128): counted vmcnt(4), 2-deep 2-buffer,
// async pre-swizzled Sx staging, Prow aliases staging. LDS 40960.
__global__ __launch_bounds__(256) void k_fused(const unsigned short* __restrict__ Mb,
    const unsigned short* __restrict__ sxT, float* __restrict__ Rpart) {
  __shared__ char lds[40960];
  char* bufJ0 = lds;            // [0,8K)
  char* bufI0 = lds + 8192;     // [8K,16K)
  char* bufJ1 = lds + 16384;    // [16K,24K)
  char* bufI1 = lds + 24576;    // [24K,32K)
  char* Prow  = lds;            // [0,32K) aliases all staging buffers
  char* Sx    = lds + 32768;    // [32K,40K)
  int t = threadIdx.x;
  int wid = t >> 6, lane = t & 63;
  int r15 = lane & 15, kgrp = lane >> 4;
  int wrj = wid >> 1, wci = wid & 1;
  int I0 = blockIdx.x * 128;
  int Jbase = blockIdx.y * 512;

  f32x4 pv[2][2];
#pragma unroll
  for (int m = 0; m < 2; ++m)
#pragma unroll
    for (int n = 0; n < 2; ++n) pv[m][n] = (f32x4){0.f, 0.f, 0.f, 0.f};

  // QK staging: linear LDS dest; pre-swizzled global source col (slot ^ (row&3)).
  int srow = wid * 16 + (lane >> 2);
  int scol = (((lane & 3) ^ ((lane >> 2) & 3)) * 8);   // elements
  int ldst = wid * 1024;
  const unsigned short* gI0 = Mb + (size_t)(I0 + srow) * CDIM + scol;
  const unsigned short* gI1 = Mb + (size_t)(I0 + 64 + srow) * CDIM + scol;

  // Sx staging geometry: wave wid covers c rows (r2*16 + wid*4 + lane/16), slot = lane&15
  int sx_c_local = wid * 4 + (lane >> 4);
  int sx_slot = lane & 15;

  for (int jt = 0; jt < 4; ++jt) {
    int J0 = Jbase + jt * 128;
    const unsigned short* gJ0 = Mb + (size_t)(J0 + srow) * CDIM + scol;
    const unsigned short* gJ1 = Mb + (size_t)(J0 + 64 + srow) * CDIM + scol;

    __syncthreads();   // prev jt's PV readers done before Sx/staging overwrite

    // Sx tile [32 c][128 j] via async gld16, source pre-swizzled:
    // LDS[c][slot] = sxT[c][(slot ^ (c&15))*8 ..]
#pragma unroll
    for (int r2 = 0; r2 < 2; ++r2) {
      int c = r2 * 16 + sx_c_local;
      int j = ((sx_slot ^ (c & 15)) * 8);
      gld16(sxT + (size_t)c * NTOT + J0 + j, Sx + (r2 * 16 + wid * 4) * 256);
    }

#define ISSUE(KS, BJ, BI)                                                      \
    { gld16(gJ0 + (KS) * 32, (BJ) + ldst);                                     \
      gld16(gJ1 + (KS) * 32, (BJ) + 4096 + ldst);                              \
      gld16(gI0 + (KS) * 32, (BI) + ldst);                                     \
      gld16(gI1 + (KS) * 32, (BI) + 4096 + ldst); }

#define QKSTEP(BJ, BI)                                                         \
    {                                                                          \
      short8 a[4], b[4];                                                       \
      _Pragma("unroll")                                                        \
      for (int m = 0; m < 4; ++m)                                              \
        a[m] = *(const short8*)((BJ) + ((wrj * 64 + m * 16 + r15) * 64 +       \
                                        ((kgrp * 16) ^ ((r15 & 3) << 4))));    \
      _Pragma("unroll")                                                        \
      for (int n = 0; n < 4; ++n)                                              \
        b[n] = *(const short8*)((BI) + ((wci * 64 + n * 16 + r15) * 64 +       \
                                        ((kgrp * 16) ^ ((r15 & 3) << 4))));    \
      _Pragma("unroll")                                                        \
      for (int m = 0; m < 4; ++m)                                              \
        _Pragma("unroll")                                                      \
        for (int n = 0; n < 4; ++n)                                            \
          acc[m][n] = __builtin_amdgcn_mfma_f32_16x16x32_bf16(a[m], b[n], acc[m][n], 0, 0, 0); \
    }

    // prologue: Sx (2) + 2-deep QK prefetch (8) outstanding
    ISSUE(0, bufJ0, bufI0);
    ISSUE(1, bufJ1, bufI1);

    f32x4 acc[4][4];
#pragma unroll
    for (int m = 0; m < 4; ++m)
#pragma unroll
      for (int n = 0; n < 4; ++n) acc[m][n] = (f32x4){0.f, 0.f, 0.f, 0.f};

    // steady state: wait only for loads issued 2 K-steps ago
#pragma unroll 1
    for (int kk = 0; kk < 14; kk += 2) {
      asm volatile("s_waitcnt vmcnt(4)" ::: "memory");
      __builtin_amdgcn_s_barrier();
      __builtin_amdgcn_sched_barrier(0);
      QKSTEP(bufJ0, bufI0);
      __builtin_amdgcn_sched_barrier(0);
      __builtin_amdgcn_s_barrier();
      ISSUE(kk + 2, bufJ0, bufI0);
      asm volatile("s_waitcnt vmcnt(4)" ::: "memory");
      __builtin_amdgcn_s_barrier();
      __builtin_amdgcn_sched_barrier(0);
      QKSTEP(bufJ1, bufI1);
      __builtin_amdgcn_sched_barrier(0);
      __builtin_amdgcn_s_barrier();
      ISSUE(kk + 3, bufJ1, bufI1);
    }
    // epilogue K-steps 14,15
    asm volatile("s_waitcnt vmcnt(4)" ::: "memory");
    __builtin_amdgcn_s_barrier();
    __builtin_amdgcn_sched_barrier(0);
    QKSTEP(bufJ0, bufI0);
    __builtin_amdgcn_sched_barrier(0);
    __builtin_amdgcn_s_barrier();
    asm volatile("s_waitcnt vmcnt(0)" ::: "memory");
    __builtin_amdgcn_s_barrier();
    __builtin_amdgcn_sched_barrier(0);
    QKSTEP(bufJ1, bufI1);
    __builtin_amdgcn_sched_barrier(0);
    __builtin_amdgcn_s_barrier();   // all QK reads done -> Prow may overwrite bufs
#undef QKSTEP
#undef ISSUE

    // acc = P^T tile: row j = wrj*64+m*16+kgrp*4+reg, col i = wci*64+n*16+r15.
#pragma unroll
    for (int m = 0; m < 4; ++m) {
#pragma unroll
      for (int n = 0; n < 4; ++n) {
        int iloc = wci * 64 + n * 16 + r15;
        int gi = I0 + iloc;
        int jloc = wrj * 64 + m * 16 + kgrp * 4;
        int gj = J0 + jloc;
        unsigned short h[4];
#pragma unroll
        for (int reg = 0; reg < 4; ++reg) {
          float v = acc[m][n][reg];
          v = v > 0.f ? v : 0.f;
          if (gj + reg == gi) v = 0.f;
          h[reg] = f2bf(v);
        }
        uint2 pk;
        pk.x = (unsigned)h[0] | ((unsigned)h[1] << 16);
        pk.y = (unsigned)h[2] | ((unsigned)h[3] << 16);
        *(uint2*)(Prow + iloc * 256 + ((jloc * 2) ^ ((iloc & 15) << 4))) = pk;
      }
    }
    __syncthreads();

    // PV: pv += Ptile(128x128) @ Sx(128x32); wave owns rows wid*32..+32
#pragma unroll
    for (int ks = 0; ks < 4; ++ks) {
      short8 a2[2], b2[2];
#pragma unroll
      for (int m2 = 0; m2 < 2; ++m2) {
        int iloc = wid * 32 + m2 * 16 + r15;
        a2[m2] = *(const short8*)(Prow + iloc * 256 +
                                  ((ks * 64 + kgrp * 16) ^ ((iloc & 15) << 4)));
      }
#pragma unroll
      for (int n2 = 0; n2 < 2; ++n2) {
        int c = n2 * 16 + r15;
        b2[n2] = *(const short8*)(Sx + c * 256 +
                                  ((ks * 64 + kgrp * 16) ^ ((c & 15) << 4)));
      }
#pragma unroll
      for (int m2 = 0; m2 < 2; ++m2)
#pragma unroll
        for (int n2 = 0; n2 < 2; ++n2)
          pv[m2][n2] = __builtin_amdgcn_mfma_f32_16x16x32_bf16(a2[m2], b2[n2], pv[m2][n2], 0, 0, 0);
    }
  }

  // write transposed Rpart[jc][c][gi]: 4 consecutive gi per lane -> float4 store
#pragma unroll
  for (int m2 = 0; m2 < 2; ++m2) {
#pragma unroll
    for (int n2 = 0; n2 < 2; ++n2) {
      int c = n2 * 16 + r15;
      if (c < 28) {
        int gi = I0 + wid * 32 + m2 * 16 + kgrp * 4;
        *(f32x4*)(&Rpart[((size_t)blockIdx.y * 28 + c) * NTOT + gi]) = pv[m2][n2];
      }
    }
  }
}

// ---------------- K6 (MFMA syrk): Gpart[kb][32][32] = Sx(:, kb-chunk) Sx^T ----------------
__global__ __launch_bounds__(256) void k_sts2(const unsigned short* __restrict__ sxbf,
    float* __restrict__ Gpart) {
  __shared__ float red[4][32][33];
  int t = threadIdx.x;
  int wv = t >> 6, lane = t & 63;
  int r15 = lane & 15, kgrp = lane >> 4;
  int kbase = blockIdx.x * 128 + wv * 32 + kgrp * 8;
  short8 a[2];
#pragma unroll
  for (int m = 0; m < 2; ++m)
    a[m] = *(const short8*)(sxbf + (size_t)(m * 16 + r15) * NTOT + kbase);
  f32x4 g4[2][2];
#pragma unroll
  for (int m = 0; m < 2; ++m)
#pragma unroll
    for (int n = 0; n < 2; ++n) {
      g4[m][n] = (f32x4){0.f, 0.f, 0.f, 0.f};
      g4[m][n] = __builtin_amdgcn_mfma_f32_16x16x32_bf16(a[m], a[n], g4[m][n], 0, 0, 0);
    }
#pragma unroll
  for (int m = 0; m < 2; ++m)
#pragma unroll
    for (int n = 0; n < 2; ++n)
#pragma unroll
      for (int reg = 0; reg < 4; ++reg)
        red[wv][m * 16 + kgrp * 4 + reg][n * 16 + r15] = g4[m][n][reg];
  __syncthreads();
  for (int idx = t; idx < 1024; idx += 256) {
    int r = idx >> 5, c = idx & 31;
    Gpart[(size_t)blockIdx.x * 1024 + idx] = red[0][r][c] + red[1][r][c] + red[2][r][c] + red[3][r][c];
  }
}

// ---------------- K7a: grid-parallel reduction of Rpart -> 128x30 partials ----------------
__global__ __launch_bounds__(64) void k_reduce1(const float* __restrict__ Rpart,
    const float* __restrict__ sT, const float* __restrict__ maxv,
    float* __restrict__ partials) {
  int t = threadIdx.x;
  int n = blockIdx.x * 64 + t;
  float rsum[28];
#pragma unroll
  for (int c = 0; c < 28; ++c) rsum[c] = 0.f;
#pragma unroll
  for (int bs = 0; bs < 16; ++bs)
#pragma unroll
    for (int c = 0; c < 28; ++c)
      rsum[c] += Rpart[((size_t)bs * 28 + c) * NTOT + n];
  float deg = rsum[0];
  float T1 = 0.f;
  float vloc[KCL];
#pragma unroll
  for (int k = 0; k < KCL; ++k) {
    float sv = sT[(size_t)k * NTOT + n];
    T1 += sv * rsum[1 + k];
    vloc[k] = deg * sv;
  }
  float mx = maxv[n];
  for (int o = 32; o; o >>= 1) {
    deg += __shfl_down(deg, o);
    T1 += __shfl_down(T1, o);
    mx += __shfl_down(mx, o);
  }
#pragma unroll
  for (int k = 0; k < KCL; ++k)
    for (int o = 32; o; o >>= 1) vloc[k] += __shfl_down(vloc[k], o);
  if (t == 0) {
    float* p = partials + blockIdx.x * 30;
    p[0] = deg; p[1] = T1; p[2] = mx;
#pragma unroll
    for (int k = 0; k < KCL; ++k) p[3 + k] = vloc[k];
  }
}

// ---------------- K7b: tiny final combine + ortho ----------------
__device__ float block_sum_1024(float v) {
  __shared__ float sc[16];
  for (int o = 32; o; o >>= 1) v += __shfl_down(v, o);
  __syncthreads();
  if ((threadIdx.x & 63) == 0) sc[threadIdx.x >> 6] = v;
  __syncthreads();
  if (threadIdx.x == 0) {
    float r = 0.f;
    for (int i = 0; i < 16; ++i) r += sc[i];
    sc[0] = r;
  }
  __syncthreads();
  return sc[0];
}

__global__ __launch_bounds__(1024) void k_final2(const float* __restrict__ partials,
    const float* __restrict__ Gpart, float* __restrict__ out) {
  __shared__ float comb[30];
  int t = threadIdx.x;
  if (t < 30) {
    float a = 0.f;
    for (int b = 0; b < 128; ++b) a += partials[b * 30 + t];
    comb[t] = a;
  }
  float val = 0.f;
  if (t < 729) {
    int k = t / 27, l = t - k * 27;
    int gidx = (k + 1) * 32 + (l + 1);
    for (int b = 0; b < 64; ++b) val += Gpart[(size_t)b * 1024 + gidx];
  }
  __syncthreads();
  float F2 = block_sum_1024(val * val);
  float F = sqrtf(F2);
  bool diag = (t < 729) && (t % 28 == 0);
  float gg = (t < 729) ? (val / F - (diag ? (1.f / sqrtf(27.f)) : 0.f)) : 0.f;
  float O2 = block_sum_1024(gg * gg);
  float ortho = sqrtf(O2);
  if (t == 0) {
    float sumDeg = comb[0], T1 = comb[1], maxsum = comb[2];
    float norm = 0.5f * sumDeg;
    float vv = 0.f;
    for (int k = 0; k < KCL; ++k) vv += comb[3 + k] * comb[3 + k];
    float c = 0.05f / (2.f * norm);
    float sm = -(T1 - c * vv) / (2.f * norm);
    float cl = -maxsum / (float)NTOT;
    out[0] = sm + cl + ortho;
    out[1] = sm;
  }
}

extern "C" void kernel_launch(void* const* d_in, const int* in_sizes, int n_in,
                              void* d_out, int out_size, void* d_ws, size_t ws_size,
                              hipStream_t stream) {
  const float* x        = (const float*)d_in[0];
  const float* clusters = (const float*)d_in[1];
  const float* alpha    = (const float*)d_in[2];
  float* out = (float*)d_out;
  float* ws  = (float*)d_ws;

  // workspace layout (float offsets)
  const size_t OFF_MBF  = 0;                                    // bf16 [8192][512]
  const size_t OFF_NCLB = (size_t)NTOT * CDIM / 2;              // bf16 [32][512]
  const size_t OFF_ST   = OFF_NCLB + (size_t)32 * CDIM / 2;     // f32 sT [27][8192]
  const size_t OFF_SXB  = OFF_ST + (size_t)NTOT * KCL;          // bf16 sxT [32][8192]
  const size_t OFF_MAXV = OFF_SXB + (size_t)32 * NTOT / 2;
  const size_t OFF_SQ   = OFF_MAXV + NTOT;                      // f32 [4][8192]
  const size_t OFF_R    = OFF_SQ + (size_t)4 * NTOT;            // Rpart: 16*28*8192 f32
  const size_t OFF_GP   = OFF_R + (size_t)16 * 28 * NTOT;       // Gpart: 64*1024 f32
  const size_t OFF_PART = OFF_GP + (size_t)64 * 1024;           // 128*30 partials

  unsigned short* mbf  = (unsigned short*)(ws + OFF_MBF);
  unsigned short* nclb = (unsigned short*)(ws + OFF_NCLB);
  unsigned short* sxbf = (unsigned short*)(ws + OFF_SXB);

  // no memsets needed: nclb rows 27-31 / sxbf rows 28-31 feed only output
  // columns >= 28, which are never read (PV write guarded c<28; k_final2
  // reads Gpart indices 1..27 only). Contents are replay-invariant.
  k_clusters<<<27, 64, 0, stream>>>(clusters, nclb);
  k_merged2<<<512, 256, 0, stream>>>(x, mbf, ws + OFF_SQ);
  k_scale<<<2048, 256, 0, stream>>>(ws + OFF_SQ, mbf);
  k_inner2<<<256, 256, 0, stream>>>(mbf, nclb, alpha,
                                    ws + OFF_ST, ws + OFF_MAXV, out + 2, sxbf);
  k_fused<<<dim3(64, 16), 256, 0, stream>>>(mbf, sxbf, ws + OFF_R);
  k_sts2<<<64, 256, 0, stream>>>(sxbf, ws + OFF_GP);
  k_reduce1<<<128, 64, 0, stream>>>(ws + OFF_R, ws + OFF_ST, ws + OFF_MAXV,
                                    ws + OFF_PART);
  k_final2<<<1, 1024, 0, stream>>>(ws + OFF_PART, ws + OFF_GP, out);
}

// Round 17
// 134.695 us; speedup vs baseline: 1.3995x; 1.0692x over previous
//
#include <hip/hip_runtime.h>

#define NTOT 8192
#define CDIM 512
#define KCL 27

typedef __attribute__((ext_vector_type(8))) short short8;
typedef __attribute__((ext_vector_type(4))) float f32x4;

static __device__ __forceinline__ unsigned short f2bf(float v) {
  union { float f; unsigned u; } z; z.f = v;
  unsigned r = (z.u + 0x7FFFu + ((z.u >> 16) & 1u)) >> 16;
  return (unsigned short)r;
}

static __device__ __forceinline__ float bf2f(unsigned short h) {
  union { unsigned u; float f; } z; z.u = ((unsigned)h) << 16;
  return z.f;
}

static __device__ __forceinline__ void gld16(const unsigned short* g, char* l) {
  __builtin_amdgcn_global_load_lds(
      (const __attribute__((address_space(1))) void*)g,
      (__attribute__((address_space(3))) void*)l, 16, 0, 0);
}

// ---------------- K2 (merged): permute(0,3,2,1) -> mbf bf16 (UNNORMALIZED) + sq-partials;
// blocks >= 512 normalize one cluster row each into nclb. ----------------
__global__ __launch_bounds__(256) void k_merged2(const float* __restrict__ x,
    const float* __restrict__ clusters, unsigned short* __restrict__ mbf,
    unsigned short* __restrict__ nclb, float* __restrict__ sqpart) {
  __shared__ float tile[64][65];
  __shared__ float part[4][64];
  __shared__ float sc[4];
  int bid = blockIdx.x;
  int t = threadIdx.x;
  if (bid >= 512) {                      // cluster-normalize branch
    int k = bid - 512;
    const float* row = clusters + (size_t)k * CDIM;
    float ss = 0.f;
    for (int c = t; c < CDIM; c += 256) { float v = row[c]; ss += v * v; }
    for (int o = 32; o; o >>= 1) ss += __shfl_down(ss, o);
    if ((t & 63) == 0) sc[t >> 6] = ss;
    __syncthreads();
    float tot = sc[0] + sc[1] + sc[2] + sc[3];
    float inv = 1.f / fmaxf(sqrtf(tot), 1e-12f);
    for (int c = t; c < CDIM; c += 256) nclb[(size_t)k * CDIM + c] = f2bf(row[c] * inv);
    return;
  }
  int bh = bid >> 2, cq = bid & 3;
  int b = bh >> 6, h = bh & 63;
  int w = t & 63, cg = t >> 6;
  const float* xb = x + (size_t)b * CDIM * 4096 + (size_t)h * 64; // xb[c*4096 + w]
  float ss = 0.f;
  for (int c0 = cq * 128; c0 < cq * 128 + 128; c0 += 64) {
#pragma unroll
    for (int q = 0; q < 16; ++q) {
      int c = cg + q * 4;
      float v = xb[(size_t)(c0 + c) * 4096 + w];
      tile[c][w] = v;
      ss += v * v;                       // partial for pixel n = b*4096 + w*64 + h
    }
    __syncthreads();
#pragma unroll
    for (int q = 0; q < 16; ++q) {
      int ww = cg + q * 4;
      int n = b * 4096 + ww * 64 + h;    // n from permute(0,3,2,1)
      mbf[(size_t)n * CDIM + c0 + w] = f2bf(tile[w][ww]);
    }
    __syncthreads();
  }
  part[cg][w] = ss;
  __syncthreads();
  if (t < 64) {
    float s = part[0][t] + part[1][t] + part[2][t] + part[3][t];
    sqpart[(size_t)cq * NTOT + bh * 64 + t] = s;   // coalesced
  }
}

// ---------------- K3 (MFMA): normalize mbf in-register (write back) + inner = mbf @ nclb^T ----------------
// Each (row, 8-col chunk) of the block's 32 rows is loaded exactly once for the MFMA:
// scale by rowivn there, feed MFMA, and store the normalized fragment back to mbf.
__global__ __launch_bounds__(256) void k_inner2(unsigned short* __restrict__ mbf,
    const unsigned short* __restrict__ nclb, const float* __restrict__ alpha_p,
    const float* __restrict__ sqpart,
    float* __restrict__ sT, float* __restrict__ maxv,
    float* __restrict__ out_cp, unsigned short* __restrict__ sxbf) {
  __shared__ float red[4][32][33];
  __shared__ float innerS[32][33];
  __shared__ float rowml[32], rowls[32], rowsum[32], rowivn[32];
  int t = threadIdx.x;
  int wv = t >> 6, lane = t & 63;
  int r15 = lane & 15, kgrp = lane >> 4;
  int I0 = blockIdx.x * 32;
  float alpha = alpha_p[0];

  if (t < 32) {                          // per-row inverse norm from sq-partials
    int n = I0 + t;
    int b = n >> 12, w = (n >> 6) & 63, h = n & 63;
    int idx = (b * 64 + h) * 64 + w;
    float s = sqpart[idx] + sqpart[NTOT + idx] + sqpart[2 * NTOT + idx] + sqpart[3 * NTOT + idx];
    rowivn[t] = 1.f / fmaxf(sqrtf(s), 1e-12f);
  }
  __syncthreads();

  f32x4 acc[2][2];
#pragma unroll
  for (int m = 0; m < 2; ++m)
#pragma unroll
    for (int n = 0; n < 2; ++n) acc[m][n] = (f32x4){0.f, 0.f, 0.f, 0.f};

#pragma unroll
  for (int ks = 0; ks < 4; ++ks) {
    int kbase = wv * 128 + ks * 32 + kgrp * 8;
    short8 a[2], b[2];
#pragma unroll
    for (int m = 0; m < 2; ++m) {
      unsigned short* p = mbf + (size_t)(I0 + m * 16 + r15) * CDIM + kbase;
      short8 raw = *(const short8*)p;
      float iv = rowivn[m * 16 + r15];
      short8 nm;
#pragma unroll
      for (int i = 0; i < 8; ++i)
        nm[i] = (short)f2bf(bf2f((unsigned short)raw[i]) * iv);
      *(short8*)p = nm;                  // write back normalized (unique writer)
      a[m] = nm;
    }
#pragma unroll
    for (int n = 0; n < 2; ++n)
      b[n] = *(const short8*)(nclb + (size_t)(n * 16 + r15) * CDIM + kbase);
#pragma unroll
    for (int m = 0; m < 2; ++m)
#pragma unroll
      for (int n = 0; n < 2; ++n)
        acc[m][n] = __builtin_amdgcn_mfma_f32_16x16x32_bf16(a[m], b[n], acc[m][n], 0, 0, 0);
  }
#pragma unroll
  for (int m = 0; m < 2; ++m)
#pragma unroll
    for (int n = 0; n < 2; ++n)
#pragma unroll
      for (int reg = 0; reg < 4; ++reg)
        red[wv][m * 16 + kgrp * 4 + reg][n * 16 + r15] = acc[m][n][reg];
  __syncthreads();
  for (int idx = t; idx < 1024; idx += 256) {
    int r = idx >> 5, c = idx & 31;
    innerS[r][c] = red[0][r][c] + red[1][r][c] + red[2][r][c] + red[3][r][c];
  }
  __syncthreads();
  if (t < 32) {
    float mi = -3.4e38f, ml = -3.4e38f;
    for (int k = 0; k < KCL; ++k) {
      float iv = innerS[t][k];
      mi = fmaxf(mi, iv);
      ml = fmaxf(ml, alpha * iv);
    }
    float sum = 0.f;
    for (int k = 0; k < KCL; ++k) sum += expf(alpha * innerS[t][k] - ml);
    rowml[t] = ml;
    rowls[t] = ml + logf(sum);
    rowsum[t] = 1.f / sum;
    maxv[I0 + t] = mi;
    sxbf[I0 + t] = 0x3F80;               // Sx row 0 = 1.0
  }
  __syncthreads();
  for (int idx = t; idx < 32 * KCL; idx += 256) {
    int r = idx / KCL, k = idx - r * KCL;
    int n = I0 + r;
    float iv = innerS[r][k];
    float sv = expf(alpha * iv - rowml[r]) * rowsum[r];
    sT[(size_t)k * NTOT + n] = sv;
    sxbf[(size_t)(k + 1) * NTOT + n] = f2bf(sv);
    int b = n >> 12, w = (n >> 6) & 63, h = n & 63;
    out_cp[(((size_t)b * KCL + k) * 64 + h) * 64 + w] = alpha * iv - rowls[r];
  }
}

// ---------------- K4 (fused): Rpart[jc][28][N] = relu(Mi Mj^T, diag=0) @ [1|S] ----------------
// Round-12/14/16 version (best validated, VGPR 128): counted vmcnt(4), 2-deep 2-buffer,
// async pre-swizzled Sx staging, Prow aliases staging. LDS 40960. UNCHANGED.
__global__ __launch_bounds__(256) void k_fused(const unsigned short* __restrict__ Mb,
    const unsigned short* __restrict__ sxT, float* __restrict__ Rpart) {
  __shared__ char lds[40960];
  char* bufJ0 = lds;            // [0,8K)
  char* bufI0 = lds + 8192;     // [8K,16K)
  char* bufJ1 = lds + 16384;    // [16K,24K)
  char* bufI1 = lds + 24576;    // [24K,32K)
  char* Prow  = lds;            // [0,32K) aliases all staging buffers
  char* Sx    = lds + 32768;    // [32K,40K)
  int t = threadIdx.x;
  int wid = t >> 6, lane = t & 63;
  int r15 = lane & 15, kgrp = lane >> 4;
  int wrj = wid >> 1, wci = wid & 1;
  int I0 = blockIdx.x * 128;
  int Jbase = blockIdx.y * 512;

  f32x4 pv[2][2];
#pragma unroll
  for (int m = 0; m < 2; ++m)
#pragma unroll
    for (int n = 0; n < 2; ++n) pv[m][n] = (f32x4){0.f, 0.f, 0.f, 0.f};

  // QK staging: linear LDS dest; pre-swizzled global source col (slot ^ (row&3)).
  int srow = wid * 16 + (lane >> 2);
  int scol = (((lane & 3) ^ ((lane >> 2) & 3)) * 8);   // elements
  int ldst = wid * 1024;
  const unsigned short* gI0 = Mb + (size_t)(I0 + srow) * CDIM + scol;
  const unsigned short* gI1 = Mb + (size_t)(I0 + 64 + srow) * CDIM + scol;

  // Sx staging geometry: wave wid covers c rows (r2*16 + wid*4 + lane/16), slot = lane&15
  int sx_c_local = wid * 4 + (lane >> 4);
  int sx_slot = lane & 15;

  for (int jt = 0; jt < 4; ++jt) {
    int J0 = Jbase + jt * 128;
    const unsigned short* gJ0 = Mb + (size_t)(J0 + srow) * CDIM + scol;
    const unsigned short* gJ1 = Mb + (size_t)(J0 + 64 + srow) * CDIM + scol;

    __syncthreads();   // prev jt's PV readers done before Sx/staging overwrite

    // Sx tile [32 c][128 j] via async gld16, source pre-swizzled:
    // LDS[c][slot] = sxT[c][(slot ^ (c&15))*8 ..]
#pragma unroll
    for (int r2 = 0; r2 < 2; ++r2) {
      int c = r2 * 16 + sx_c_local;
      int j = ((sx_slot ^ (c & 15)) * 8);
      gld16(sxT + (size_t)c * NTOT + J0 + j, Sx + (r2 * 16 + wid * 4) * 256);
    }

#define ISSUE(KS, BJ, BI)                                                      \
    { gld16(gJ0 + (KS) * 32, (BJ) + ldst);                                     \
      gld16(gJ1 + (KS) * 32, (BJ) + 4096 + ldst);                              \
      gld16(gI0 + (KS) * 32, (BI) + ldst);                                     \
      gld16(gI1 + (KS) * 32, (BI) + 4096 + ldst); }

#define QKSTEP(BJ, BI)                                                         \
    {                                                                          \
      short8 a[4], b[4];                                                       \
      _Pragma("unroll")                                                        \
      for (int m = 0; m < 4; ++m)                                              \
        a[m] = *(const short8*)((BJ) + ((wrj * 64 + m * 16 + r15) * 64 +       \
                                        ((kgrp * 16) ^ ((r15 & 3) << 4))));    \
      _Pragma("unroll")                                                        \
      for (int n = 0; n < 4; ++n)                                              \
        b[n] = *(const short8*)((BI) + ((wci * 64 + n * 16 + r15) * 64 +       \
                                        ((kgrp * 16) ^ ((r15 & 3) << 4))));    \
      _Pragma("unroll")                                                        \
      for (int m = 0; m < 4; ++m)                                              \
        _Pragma("unroll")                                                      \
        for (int n = 0; n < 4; ++n)                                            \
          acc[m][n] = __builtin_amdgcn_mfma_f32_16x16x32_bf16(a[m], b[n], acc[m][n], 0, 0, 0); \
    }

    // prologue: Sx (2) + 2-deep QK prefetch (8) outstanding
    ISSUE(0, bufJ0, bufI0);
    ISSUE(1, bufJ1, bufI1);

    f32x4 acc[4][4];
#pragma unroll
    for (int m = 0; m < 4; ++m)
#pragma unroll
      for (int n = 0; n < 4; ++n) acc[m][n] = (f32x4){0.f, 0.f, 0.f, 0.f};

    // steady state: wait only for loads issued 2 K-steps ago
#pragma unroll 1
    for (int kk = 0; kk < 14; kk += 2) {
      asm volatile("s_waitcnt vmcnt(4)" ::: "memory");
      __builtin_amdgcn_s_barrier();
      __builtin_amdgcn_sched_barrier(0);
      QKSTEP(bufJ0, bufI0);
      __builtin_amdgcn_sched_barrier(0);
      __builtin_amdgcn_s_barrier();
      ISSUE(kk + 2, bufJ0, bufI0);
      asm volatile("s_waitcnt vmcnt(4)" ::: "memory");
      __builtin_amdgcn_s_barrier();
      __builtin_amdgcn_sched_barrier(0);
      QKSTEP(bufJ1, bufI1);
      __builtin_amdgcn_sched_barrier(0);
      __builtin_amdgcn_s_barrier();
      ISSUE(kk + 3, bufJ1, bufI1);
    }
    // epilogue K-steps 14,15
    asm volatile("s_waitcnt vmcnt(4)" ::: "memory");
    __builtin_amdgcn_s_barrier();
    __builtin_amdgcn_sched_barrier(0);
    QKSTEP(bufJ0, bufI0);
    __builtin_amdgcn_sched_barrier(0);
    __builtin_amdgcn_s_barrier();
    asm volatile("s_waitcnt vmcnt(0)" ::: "memory");
    __builtin_amdgcn_s_barrier();
    __builtin_amdgcn_sched_barrier(0);
    QKSTEP(bufJ1, bufI1);
    __builtin_amdgcn_sched_barrier(0);
    __builtin_amdgcn_s_barrier();   // all QK reads done -> Prow may overwrite bufs
#undef QKSTEP
#undef ISSUE

    // acc = P^T tile: row j = wrj*64+m*16+kgrp*4+reg, col i = wci*64+n*16+r15.
#pragma unroll
    for (int m = 0; m < 4; ++m) {
#pragma unroll
      for (int n = 0; n < 4; ++n) {
        int iloc = wci * 64 + n * 16 + r15;
        int gi = I0 + iloc;
        int jloc = wrj * 64 + m * 16 + kgrp * 4;
        int gj = J0 + jloc;
        unsigned short h[4];
#pragma unroll
        for (int reg = 0; reg < 4; ++reg) {
          float v = acc[m][n][reg];
          v = v > 0.f ? v : 0.f;
          if (gj + reg == gi) v = 0.f;
          h[reg] = f2bf(v);
        }
        uint2 pk;
        pk.x = (unsigned)h[0] | ((unsigned)h[1] << 16);
        pk.y = (unsigned)h[2] | ((unsigned)h[3] << 16);
        *(uint2*)(Prow + iloc * 256 + ((jloc * 2) ^ ((iloc & 15) << 4))) = pk;
      }
    }
    __syncthreads();

    // PV: pv += Ptile(128x128) @ Sx(128x32); wave owns rows wid*32..+32
#pragma unroll
    for (int ks = 0; ks < 4; ++ks) {
      short8 a2[2], b2[2];
#pragma unroll
      for (int m2 = 0; m2 < 2; ++m2) {
        int iloc = wid * 32 + m2 * 16 + r15;
        a2[m2] = *(const short8*)(Prow + iloc * 256 +
                                  ((ks * 64 + kgrp * 16) ^ ((iloc & 15) << 4)));
      }
#pragma unroll
      for (int n2 = 0; n2 < 2; ++n2) {
        int c = n2 * 16 + r15;
        b2[n2] = *(const short8*)(Sx + c * 256 +
                                  ((ks * 64 + kgrp * 16) ^ ((c & 15) << 4)));
      }
#pragma unroll
      for (int m2 = 0; m2 < 2; ++m2)
#pragma unroll
        for (int n2 = 0; n2 < 2; ++n2)
          pv[m2][n2] = __builtin_amdgcn_mfma_f32_16x16x32_bf16(a2[m2], b2[n2], pv[m2][n2], 0, 0, 0);
    }
  }

  // write transposed Rpart[jc][c][gi]: 4 consecutive gi per lane -> float4 store
#pragma unroll
  for (int m2 = 0; m2 < 2; ++m2) {
#pragma unroll
    for (int n2 = 0; n2 < 2; ++n2) {
      int c = n2 * 16 + r15;
      if (c < 28) {
        int gi = I0 + wid * 32 + m2 * 16 + kgrp * 4;
        *(f32x4*)(&Rpart[((size_t)blockIdx.y * 28 + c) * NTOT + gi]) = pv[m2][n2];
      }
    }
  }
}

// ---------------- K5 (merged tail): blocks 0..63 = syrk Gpart; blocks 64..95 = Rpart reduction ----------------
__global__ __launch_bounds__(256) void k_tail(const unsigned short* __restrict__ sxbf,
    const float* __restrict__ Rpart, const float* __restrict__ sT,
    const float* __restrict__ maxv, float* __restrict__ Gpart,
    float* __restrict__ partials) {
  __shared__ float red[4][32][33];
  __shared__ float red2[4][30];
  int bid = blockIdx.x;
  int t = threadIdx.x;
  int wv = t >> 6, lane = t & 63;
  if (bid < 64) {
    // syrk: Gpart[bid][32][32] = Sx(:, bid-chunk) Sx^T
    int r15 = lane & 15, kgrp = lane >> 4;
    int kbase = bid * 128 + wv * 32 + kgrp * 8;
    short8 a[2];
#pragma unroll
    for (int m = 0; m < 2; ++m)
      a[m] = *(const short8*)(sxbf + (size_t)(m * 16 + r15) * NTOT + kbase);
    f32x4 g4[2][2];
#pragma unroll
    for (int m = 0; m < 2; ++m)
#pragma unroll
      for (int n = 0; n < 2; ++n) {
        g4[m][n] = (f32x4){0.f, 0.f, 0.f, 0.f};
        g4[m][n] = __builtin_amdgcn_mfma_f32_16x16x32_bf16(a[m], a[n], g4[m][n], 0, 0, 0);
      }
#pragma unroll
    for (int m = 0; m < 2; ++m)
#pragma unroll
      for (int n = 0; n < 2; ++n)
#pragma unroll
        for (int reg = 0; reg < 4; ++reg)
          red[wv][m * 16 + kgrp * 4 + reg][n * 16 + r15] = g4[m][n][reg];
    __syncthreads();
    for (int idx = t; idx < 1024; idx += 256) {
      int r = idx >> 5, c = idx & 31;
      Gpart[(size_t)bid * 1024 + idx] = red[0][r][c] + red[1][r][c] + red[2][r][c] + red[3][r][c];
    }
    return;
  }
  // reduction: n = (bid-64)*256 + t
  int n = (bid - 64) * 256 + t;
  float rsum[28];
#pragma unroll
  for (int c = 0; c < 28; ++c) rsum[c] = 0.f;
#pragma unroll
  for (int bs = 0; bs < 16; ++bs)
#pragma unroll
    for (int c = 0; c < 28; ++c)
      rsum[c] += Rpart[((size_t)bs * 28 + c) * NTOT + n];
  float deg = rsum[0];
  float T1 = 0.f;
  float vloc[KCL];
#pragma unroll
  for (int k = 0; k < KCL; ++k) {
    float sv = sT[(size_t)k * NTOT + n];
    T1 += sv * rsum[1 + k];
    vloc[k] = deg * sv;
  }
  float mx = maxv[n];
  for (int o = 32; o; o >>= 1) {
    deg += __shfl_down(deg, o);
    T1 += __shfl_down(T1, o);
    mx += __shfl_down(mx, o);
  }
#pragma unroll
  for (int k = 0; k < KCL; ++k)
    for (int o = 32; o; o >>= 1) vloc[k] += __shfl_down(vloc[k], o);
  if (lane == 0) {
    red2[wv][0] = deg; red2[wv][1] = T1; red2[wv][2] = mx;
#pragma unroll
    for (int k = 0; k < KCL; ++k) red2[wv][3 + k] = vloc[k];
  }
  __syncthreads();
  if (t < 30)
    partials[(bid - 64) * 30 + t] = red2[0][t] + red2[1][t] + red2[2][t] + red2[3][t];
}

// ---------------- K7b: tiny final combine + ortho ----------------
__device__ float block_sum_1024(float v) {
  __shared__ float sc[16];
  for (int o = 32; o; o >>= 1) v += __shfl_down(v, o);
  __syncthreads();
  if ((threadIdx.x & 63) == 0) sc[threadIdx.x >> 6] = v;
  __syncthreads();
  if (threadIdx.x == 0) {
    float r = 0.f;
    for (int i = 0; i < 16; ++i) r += sc[i];
    sc[0] = r;
  }
  __syncthreads();
  return sc[0];
}

__global__ __launch_bounds__(1024) void k_final2(const float* __restrict__ partials,
    const float* __restrict__ Gpart, float* __restrict__ out) {
  __shared__ float comb[30];
  int t = threadIdx.x;
  if (t < 30) {
    float a = 0.f;
    for (int b = 0; b < 32; ++b) a += partials[b * 30 + t];
    comb[t] = a;
  }
  float val = 0.f;
  if (t < 729) {
    int k = t / 27, l = t - k * 27;
    int gidx = (k + 1) * 32 + (l + 1);
    for (int b = 0; b < 64; ++b) val += Gpart[(size_t)b * 1024 + gidx];
  }
  __syncthreads();
  float F2 = block_sum_1024(val * val);
  float F = sqrtf(F2);
  bool diag = (t < 729) && (t % 28 == 0);
  float gg = (t < 729) ? (val / F - (diag ? (1.f / sqrtf(27.f)) : 0.f)) : 0.f;
  float O2 = block_sum_1024(gg * gg);
  float ortho = sqrtf(O2);
  if (t == 0) {
    float sumDeg = comb[0], T1 = comb[1], maxsum = comb[2];
    float norm = 0.5f * sumDeg;
    float vv = 0.f;
    for (int k = 0; k < KCL; ++k) vv += comb[3 + k] * comb[3 + k];
    float c = 0.05f / (2.f * norm);
    float sm = -(T1 - c * vv) / (2.f * norm);
    float cl = -maxsum / (float)NTOT;
    out[0] = sm + cl + ortho;
    out[1] = sm;
  }
}

extern "C" void kernel_launch(void* const* d_in, const int* in_sizes, int n_in,
                              void* d_out, int out_size, void* d_ws, size_t ws_size,
                              hipStream_t stream) {
  const float* x        = (const float*)d_in[0];
  const float* clusters = (const float*)d_in[1];
  const float* alpha    = (const float*)d_in[2];
  float* out = (float*)d_out;
  float* ws  = (float*)d_ws;

  // workspace layout (float offsets)
  const size_t OFF_MBF  = 0;                                    // bf16 [8192][512]
  const size_t OFF_NCLB = (size_t)NTOT * CDIM / 2;              // bf16 [32][512]
  const size_t OFF_ST   = OFF_NCLB + (size_t)32 * CDIM / 2;     // f32 sT [27][8192]
  const size_t OFF_SXB  = OFF_ST + (size_t)NTOT * KCL;          // bf16 sxT [32][8192]
  const size_t OFF_MAXV = OFF_SXB + (size_t)32 * NTOT / 2;
  const size_t OFF_SQ   = OFF_MAXV + NTOT;                      // f32 [4][8192]
  const size_t OFF_R    = OFF_SQ + (size_t)4 * NTOT;            // Rpart: 16*28*8192 f32
  const size_t OFF_GP   = OFF_R + (size_t)16 * 28 * NTOT;       // Gpart: 64*1024 f32
  const size_t OFF_PART = OFF_GP + (size_t)64 * 1024;           // 32*30 partials

  unsigned short* mbf  = (unsigned short*)(ws + OFF_MBF);
  unsigned short* nclb = (unsigned short*)(ws + OFF_NCLB);
  unsigned short* sxbf = (unsigned short*)(ws + OFF_SXB);

  // no memsets needed: nclb rows 27-31 / sxbf rows 28-31 feed only output
  // columns >= 28, which are never read. Contents are replay-invariant.
  k_merged2<<<539, 256, 0, stream>>>(x, clusters, mbf, nclb, ws + OFF_SQ);
  k_inner2<<<256, 256, 0, stream>>>(mbf, nclb, alpha, ws + OFF_SQ,
                                    ws + OFF_ST, ws + OFF_MAXV, out + 2, sxbf);
  k_fused<<<dim3(64, 16), 256, 0, stream>>>(mbf, sxbf, ws + OFF_R);
  k_tail<<<96, 256, 0, stream>>>(sxbf, ws + OFF_R, ws + OFF_ST, ws + OFF_MAXV,
                                 ws + OFF_GP, ws + OFF_PART);
  k_final2<<<1, 1024, 0, stream>>>(ws + OFF_PART, ws + OFF_GP, out);
}

// Round 18
// 130.227 us; speedup vs baseline: 1.4475x; 1.0343x over previous
//
#include <hip/hip_runtime.h>

#define NTOT 8192
#define CDIM 512
#define KCL 27

typedef __attribute__((ext_vector_type(8))) short short8;
typedef __attribute__((ext_vector_type(4))) float f32x4;

static __device__ __forceinline__ unsigned short f2bf(float v) {
  union { float f; unsigned u; } z; z.f = v;
  unsigned r = (z.u + 0x7FFFu + ((z.u >> 16) & 1u)) >> 16;
  return (unsigned short)r;
}

static __device__ __forceinline__ float bf2f(unsigned short h) {
  union { unsigned u; float f; } z; z.u = ((unsigned)h) << 16;
  return z.f;
}

static __device__ __forceinline__ void gld16(const unsigned short* g, char* l) {
  __builtin_amdgcn_global_load_lds(
      (const __attribute__((address_space(1))) void*)g,
      (__attribute__((address_space(3))) void*)l, 16, 0, 0);
}

// ---------------- K2 (merged): permute(0,3,2,1) -> mbf bf16 (UNNORMALIZED) + sq-partials;
// blocks >= 512 normalize one cluster row each into nclb. ----------------
__global__ __launch_bounds__(256) void k_merged2(const float* __restrict__ x,
    const float* __restrict__ clusters, unsigned short* __restrict__ mbf,
    unsigned short* __restrict__ nclb, float* __restrict__ sqpart) {
  __shared__ float tile[64][65];
  __shared__ float part[4][64];
  __shared__ float sc[4];
  int bid = blockIdx.x;
  int t = threadIdx.x;
  if (bid >= 512) {                      // cluster-normalize branch
    int k = bid - 512;
    const float* row = clusters + (size_t)k * CDIM;
    float ss = 0.f;
    for (int c = t; c < CDIM; c += 256) { float v = row[c]; ss += v * v; }
    for (int o = 32; o; o >>= 1) ss += __shfl_down(ss, o);
    if ((t & 63) == 0) sc[t >> 6] = ss;
    __syncthreads();
    float tot = sc[0] + sc[1] + sc[2] + sc[3];
    float inv = 1.f / fmaxf(sqrtf(tot), 1e-12f);
    for (int c = t; c < CDIM; c += 256) nclb[(size_t)k * CDIM + c] = f2bf(row[c] * inv);
    return;
  }
  int bh = bid >> 2, cq = bid & 3;
  int b = bh >> 6, h = bh & 63;
  int w = t & 63, cg = t >> 6;
  const float* xb = x + (size_t)b * CDIM * 4096 + (size_t)h * 64; // xb[c*4096 + w]
  float ss = 0.f;
  for (int c0 = cq * 128; c0 < cq * 128 + 128; c0 += 64) {
#pragma unroll
    for (int q = 0; q < 16; ++q) {
      int c = cg + q * 4;
      float v = xb[(size_t)(c0 + c) * 4096 + w];
      tile[c][w] = v;
      ss += v * v;                       // partial for pixel n = b*4096 + w*64 + h
    }
    __syncthreads();
#pragma unroll
    for (int q = 0; q < 16; ++q) {
      int ww = cg + q * 4;
      int n = b * 4096 + ww * 64 + h;    // n from permute(0,3,2,1)
      mbf[(size_t)n * CDIM + c0 + w] = f2bf(tile[w][ww]);
    }
    __syncthreads();
  }
  part[cg][w] = ss;
  __syncthreads();
  if (t < 64) {
    float s = part[0][t] + part[1][t] + part[2][t] + part[3][t];
    sqpart[(size_t)cq * NTOT + bh * 64 + t] = s;   // coalesced
  }
}

// ---------------- K3 (MFMA): normalize mbf in-register (write back) + inner = mbf @ nclb^T ----------------
__global__ __launch_bounds__(256) void k_inner2(unsigned short* __restrict__ mbf,
    const unsigned short* __restrict__ nclb, const float* __restrict__ alpha_p,
    const float* __restrict__ sqpart,
    float* __restrict__ sT, float* __restrict__ maxv,
    float* __restrict__ out_cp, unsigned short* __restrict__ sxbf) {
  __shared__ float red[4][32][33];
  __shared__ float innerS[32][33];
  __shared__ float rowml[32], rowls[32], rowsum[32], rowivn[32];
  int t = threadIdx.x;
  int wv = t >> 6, lane = t & 63;
  int r15 = lane & 15, kgrp = lane >> 4;
  int I0 = blockIdx.x * 32;
  float alpha = alpha_p[0];

  if (t < 32) {                          // per-row inverse norm from sq-partials
    int n = I0 + t;
    int b = n >> 12, w = (n >> 6) & 63, h = n & 63;
    int idx = (b * 64 + h) * 64 + w;
    float s = sqpart[idx] + sqpart[NTOT + idx] + sqpart[2 * NTOT + idx] + sqpart[3 * NTOT + idx];
    rowivn[t] = 1.f / fmaxf(sqrtf(s), 1e-12f);
  }
  __syncthreads();

  f32x4 acc[2][2];
#pragma unroll
  for (int m = 0; m < 2; ++m)
#pragma unroll
    for (int n = 0; n < 2; ++n) acc[m][n] = (f32x4){0.f, 0.f, 0.f, 0.f};

#pragma unroll
  for (int ks = 0; ks < 4; ++ks) {
    int kbase = wv * 128 + ks * 32 + kgrp * 8;
    short8 a[2], b[2];
#pragma unroll
    for (int m = 0; m < 2; ++m) {
      unsigned short* p = mbf + (size_t)(I0 + m * 16 + r15) * CDIM + kbase;
      short8 raw = *(const short8*)p;
      float iv = rowivn[m * 16 + r15];
      short8 nm;
#pragma unroll
      for (int i = 0; i < 8; ++i)
        nm[i] = (short)f2bf(bf2f((unsigned short)raw[i]) * iv);
      *(short8*)p = nm;                  // write back normalized (unique writer)
      a[m] = nm;
    }
#pragma unroll
    for (int n = 0; n < 2; ++n)
      b[n] = *(const short8*)(nclb + (size_t)(n * 16 + r15) * CDIM + kbase);
#pragma unroll
    for (int m = 0; m < 2; ++m)
#pragma unroll
      for (int n = 0; n < 2; ++n)
        acc[m][n] = __builtin_amdgcn_mfma_f32_16x16x32_bf16(a[m], b[n], acc[m][n], 0, 0, 0);
  }
#pragma unroll
  for (int m = 0; m < 2; ++m)
#pragma unroll
    for (int n = 0; n < 2; ++n)
#pragma unroll
      for (int reg = 0; reg < 4; ++reg)
        red[wv][m * 16 + kgrp * 4 + reg][n * 16 + r15] = acc[m][n][reg];
  __syncthreads();
  for (int idx = t; idx < 1024; idx += 256) {
    int r = idx >> 5, c = idx & 31;
    innerS[r][c] = red[0][r][c] + red[1][r][c] + red[2][r][c] + red[3][r][c];
  }
  __syncthreads();
  if (t < 32) {
    float mi = -3.4e38f, ml = -3.4e38f;
    for (int k = 0; k < KCL; ++k) {
      float iv = innerS[t][k];
      mi = fmaxf(mi, iv);
      ml = fmaxf(ml, alpha * iv);
    }
    float sum = 0.f;
    for (int k = 0; k < KCL; ++k) sum += expf(alpha * innerS[t][k] - ml);
    rowml[t] = ml;
    rowls[t] = ml + logf(sum);
    rowsum[t] = 1.f / sum;
    maxv[I0 + t] = mi;
    sxbf[I0 + t] = 0x3F80;               // Sx row 0 = 1.0
  }
  __syncthreads();
  for (int idx = t; idx < 32 * KCL; idx += 256) {
    int r = idx / KCL, k = idx - r * KCL;
    int n = I0 + r;
    float iv = innerS[r][k];
    float sv = expf(alpha * iv - rowml[r]) * rowsum[r];
    sT[(size_t)k * NTOT + n] = sv;
    sxbf[(size_t)(k + 1) * NTOT + n] = f2bf(sv);
    int b = n >> 12, w = (n >> 6) & 63, h = n & 63;
    out_cp[(((size_t)b * KCL + k) * 64 + h) * 64 + w] = alpha * iv - rowls[r];
  }
}

// ---------------- K4 (fused): Rpart[jc][28][N] = relu(Mi Mj^T, diag=0) @ [1|S] ----------------
// Round-16 structure; QK staging swizzle key changed row&3 -> (row>>1)&3 so each
// consecutive-8-lane ds_read_b128 phase covers all four 16B slot groups (bank-
// conflict-free by construction; involution preserved on both sides).
__global__ __launch_bounds__(256) void k_fused(const unsigned short* __restrict__ Mb,
    const unsigned short* __restrict__ sxT, float* __restrict__ Rpart) {
  __shared__ char lds[40960];
  char* bufJ0 = lds;            // [0,8K)
  char* bufI0 = lds + 8192;     // [8K,16K)
  char* bufJ1 = lds + 16384;    // [16K,24K)
  char* bufI1 = lds + 24576;    // [24K,32K)
  char* Prow  = lds;            // [0,32K) aliases all staging buffers
  char* Sx    = lds + 32768;    // [32K,40K)
  int t = threadIdx.x;
  int wid = t >> 6, lane = t & 63;
  int r15 = lane & 15, kgrp = lane >> 4;
  int wrj = wid >> 1, wci = wid & 1;
  int I0 = blockIdx.x * 128;
  int Jbase = blockIdx.y * 512;

  f32x4 pv[2][2];
#pragma unroll
  for (int m = 0; m < 2; ++m)
#pragma unroll
    for (int n = 0; n < 2; ++n) pv[m][n] = (f32x4){0.f, 0.f, 0.f, 0.f};

  // QK staging: linear LDS dest; pre-swizzled global source col (slot ^ ((row>>1)&3)).
  // LDS row = wid*16 + lane/4, so key = ((lane>>2)>>1)&3 = (lane>>3)&3.
  int srow = wid * 16 + (lane >> 2);
  int scol = (((lane & 3) ^ ((lane >> 3) & 3)) * 8);   // elements
  int ldst = wid * 1024;
  const unsigned short* gI0 = Mb + (size_t)(I0 + srow) * CDIM + scol;
  const unsigned short* gI1 = Mb + (size_t)(I0 + 64 + srow) * CDIM + scol;

  // Sx staging geometry: wave wid covers c rows (r2*16 + wid*4 + lane/16), slot = lane&15
  int sx_c_local = wid * 4 + (lane >> 4);
  int sx_slot = lane & 15;

  for (int jt = 0; jt < 4; ++jt) {
    int J0 = Jbase + jt * 128;
    const unsigned short* gJ0 = Mb + (size_t)(J0 + srow) * CDIM + scol;
    const unsigned short* gJ1 = Mb + (size_t)(J0 + 64 + srow) * CDIM + scol;

    __syncthreads();   // prev jt's PV readers done before Sx/staging overwrite

    // Sx tile [32 c][128 j] via async gld16, source pre-swizzled:
    // LDS[c][slot] = sxT[c][(slot ^ (c&15))*8 ..]
#pragma unroll
    for (int r2 = 0; r2 < 2; ++r2) {
      int c = r2 * 16 + sx_c_local;
      int j = ((sx_slot ^ (c & 15)) * 8);
      gld16(sxT + (size_t)c * NTOT + J0 + j, Sx + (r2 * 16 + wid * 4) * 256);
    }

#define ISSUE(KS, BJ, BI)                                                      \
    { gld16(gJ0 + (KS) * 32, (BJ) + ldst);                                     \
      gld16(gJ1 + (KS) * 32, (BJ) + 4096 + ldst);                              \
      gld16(gI0 + (KS) * 32, (BI) + ldst);                                     \
      gld16(gI1 + (KS) * 32, (BI) + 4096 + ldst); }

#define QKSTEP(BJ, BI)                                                         \
    {                                                                          \
      short8 a[4], b[4];                                                       \
      _Pragma("unroll")                                                        \
      for (int m = 0; m < 4; ++m)                                              \
        a[m] = *(const short8*)((BJ) + ((wrj * 64 + m * 16 + r15) * 64 +       \
                                        ((kgrp * 16) ^ (((r15 >> 1) & 3) << 4)))); \
      _Pragma("unroll")                                                        \
      for (int n = 0; n < 4; ++n)                                              \
        b[n] = *(const short8*)((BI) + ((wci * 64 + n * 16 + r15) * 64 +       \
                                        ((kgrp * 16) ^ (((r15 >> 1) & 3) << 4)))); \
      _Pragma("unroll")                                                        \
      for (int m = 0; m < 4; ++m)                                              \
        _Pragma("unroll")                                                      \
        for (int n = 0; n < 4; ++n)                                            \
          acc[m][n] = __builtin_amdgcn_mfma_f32_16x16x32_bf16(a[m], b[n], acc[m][n], 0, 0, 0); \
    }

    // prologue: Sx (2) + 2-deep QK prefetch (8) outstanding
    ISSUE(0, bufJ0, bufI0);
    ISSUE(1, bufJ1, bufI1);

    f32x4 acc[4][4];
#pragma unroll
    for (int m = 0; m < 4; ++m)
#pragma unroll
      for (int n = 0; n < 4; ++n) acc[m][n] = (f32x4){0.f, 0.f, 0.f, 0.f};

    // steady state: wait only for loads issued 2 K-steps ago
#pragma unroll 1
    for (int kk = 0; kk < 14; kk += 2) {
      asm volatile("s_waitcnt vmcnt(4)" ::: "memory");
      __builtin_amdgcn_s_barrier();
      __builtin_amdgcn_sched_barrier(0);
      QKSTEP(bufJ0, bufI0);
      __builtin_amdgcn_sched_barrier(0);
      __builtin_amdgcn_s_barrier();
      ISSUE(kk + 2, bufJ0, bufI0);
      asm volatile("s_waitcnt vmcnt(4)" ::: "memory");
      __builtin_amdgcn_s_barrier();
      __builtin_amdgcn_sched_barrier(0);
      QKSTEP(bufJ1, bufI1);
      __builtin_amdgcn_sched_barrier(0);
      __builtin_amdgcn_s_barrier();
      ISSUE(kk + 3, bufJ1, bufI1);
    }
    // epilogue K-steps 14,15
    asm volatile("s_waitcnt vmcnt(4)" ::: "memory");
    __builtin_amdgcn_s_barrier();
    __builtin_amdgcn_sched_barrier(0);
    QKSTEP(bufJ0, bufI0);
    __builtin_amdgcn_sched_barrier(0);
    __builtin_amdgcn_s_barrier();
    asm volatile("s_waitcnt vmcnt(0)" ::: "memory");
    __builtin_amdgcn_s_barrier();
    __builtin_amdgcn_sched_barrier(0);
    QKSTEP(bufJ1, bufI1);
    __builtin_amdgcn_sched_barrier(0);
    __builtin_amdgcn_s_barrier();   // all QK reads done -> Prow may overwrite bufs
#undef QKSTEP
#undef ISSUE

    // acc = P^T tile: row j = wrj*64+m*16+kgrp*4+reg, col i = wci*64+n*16+r15.
#pragma unroll
    for (int m = 0; m < 4; ++m) {
#pragma unroll
      for (int n = 0; n < 4; ++n) {
        int iloc = wci * 64 + n * 16 + r15;
        int gi = I0 + iloc;
        int jloc = wrj * 64 + m * 16 + kgrp * 4;
        int gj = J0 + jloc;
        unsigned short h[4];
#pragma unroll
        for (int reg = 0; reg < 4; ++reg) {
          float v = acc[m][n][reg];
          v = v > 0.f ? v : 0.f;
          if (gj + reg == gi) v = 0.f;
          h[reg] = f2bf(v);
        }
        uint2 pk;
        pk.x = (unsigned)h[0] | ((unsigned)h[1] << 16);
        pk.y = (unsigned)h[2] | ((unsigned)h[3] << 16);
        *(uint2*)(Prow + iloc * 256 + ((jloc * 2) ^ ((iloc & 15) << 4))) = pk;
      }
    }
    __syncthreads();

    // PV: pv += Ptile(128x128) @ Sx(128x32); wave owns rows wid*32..+32
#pragma unroll
    for (int ks = 0; ks < 4; ++ks) {
      short8 a2[2], b2[2];
#pragma unroll
      for (int m2 = 0; m2 < 2; ++m2) {
        int iloc = wid * 32 + m2 * 16 + r15;
        a2[m2] = *(const short8*)(Prow + iloc * 256 +
                                  ((ks * 64 + kgrp * 16) ^ ((iloc & 15) << 4)));
      }
#pragma unroll
      for (int n2 = 0; n2 < 2; ++n2) {
        int c = n2 * 16 + r15;
        b2[n2] = *(const short8*)(Sx + c * 256 +
                                  ((ks * 64 + kgrp * 16) ^ ((c & 15) << 4)));
      }
#pragma unroll
      for (int m2 = 0; m2 < 2; ++m2)
#pragma unroll
        for (int n2 = 0; n2 < 2; ++n2)
          pv[m2][n2] = __builtin_amdgcn_mfma_f32_16x16x32_bf16(a2[m2], b2[n2], pv[m2][n2], 0, 0, 0);
    }
  }

  // write transposed Rpart[jc][c][gi]: 4 consecutive gi per lane -> float4 store
#pragma unroll
  for (int m2 = 0; m2 < 2; ++m2) {
#pragma unroll
    for (int n2 = 0; n2 < 2; ++n2) {
      int c = n2 * 16 + r15;
      if (c < 28) {
        int gi = I0 + wid * 32 + m2 * 16 + kgrp * 4;
        *(f32x4*)(&Rpart[((size_t)blockIdx.y * 28 + c) * NTOT + gi]) = pv[m2][n2];
      }
    }
  }
}

// ---------------- K5 (merged tail): blocks 0..63 = syrk Gpart; blocks 64..95 = Rpart reduction ----------------
__global__ __launch_bounds__(256) void k_tail(const unsigned short* __restrict__ sxbf,
    const float* __restrict__ Rpart, const float* __restrict__ sT,
    const float* __restrict__ maxv, float* __restrict__ Gpart,
    float* __restrict__ partials) {
  __shared__ float red[4][32][33];
  __shared__ float red2[4][30];
  int bid = blockIdx.x;
  int t = threadIdx.x;
  int wv = t >> 6, lane = t & 63;
  if (bid < 64) {
    // syrk: Gpart[bid][32][32] = Sx(:, bid-chunk) Sx^T
    int r15 = lane & 15, kgrp = lane >> 4;
    int kbase = bid * 128 + wv * 32 + kgrp * 8;
    short8 a[2];
#pragma unroll
    for (int m = 0; m < 2; ++m)
      a[m] = *(const short8*)(sxbf + (size_t)(m * 16 + r15) * NTOT + kbase);
    f32x4 g4[2][2];
#pragma unroll
    for (int m = 0; m < 2; ++m)
#pragma unroll
      for (int n = 0; n < 2; ++n) {
        g4[m][n] = (f32x4){0.f, 0.f, 0.f, 0.f};
        g4[m][n] = __builtin_amdgcn_mfma_f32_16x16x32_bf16(a[m], a[n], g4[m][n], 0, 0, 0);
      }
#pragma unroll
    for (int m = 0; m < 2; ++m)
#pragma unroll
      for (int n = 0; n < 2; ++n)
#pragma unroll
        for (int reg = 0; reg < 4; ++reg)
          red[wv][m * 16 + kgrp * 4 + reg][n * 16 + r15] = g4[m][n][reg];
    __syncthreads();
    for (int idx = t; idx < 1024; idx += 256) {
      int r = idx >> 5, c = idx & 31;
      Gpart[(size_t)bid * 1024 + idx] = red[0][r][c] + red[1][r][c] + red[2][r][c] + red[3][r][c];
    }
    return;
  }
  // reduction: n = (bid-64)*256 + t
  int n = (bid - 64) * 256 + t;
  float rsum[28];
#pragma unroll
  for (int c = 0; c < 28; ++c) rsum[c] = 0.f;
#pragma unroll
  for (int bs = 0; bs < 16; ++bs)
#pragma unroll
    for (int c = 0; c < 28; ++c)
      rsum[c] += Rpart[((size_t)bs * 28 + c) * NTOT + n];
  float deg = rsum[0];
  float T1 = 0.f;
  float vloc[KCL];
#pragma unroll
  for (int k = 0; k < KCL; ++k) {
    float sv = sT[(size_t)k * NTOT + n];
    T1 += sv * rsum[1 + k];
    vloc[k] = deg * sv;
  }
  float mx = maxv[n];
  for (int o = 32; o; o >>= 1) {
    deg += __shfl_down(deg, o);
    T1 += __shfl_down(T1, o);
    mx += __shfl_down(mx, o);
  }
#pragma unroll
  for (int k = 0; k < KCL; ++k)
    for (int o = 32; o; o >>= 1) vloc[k] += __shfl_down(vloc[k], o);
  if (lane == 0) {
    red2[wv][0] = deg; red2[wv][1] = T1; red2[wv][2] = mx;
#pragma unroll
    for (int k = 0; k < KCL; ++k) red2[wv][3 + k] = vloc[k];
  }
  __syncthreads();
  if (t < 30)
    partials[(bid - 64) * 30 + t] = red2[0][t] + red2[1][t] + red2[2][t] + red2[3][t];
}

// ---------------- K7b: tiny final combine + ortho ----------------
__device__ float block_sum_1024(float v) {
  __shared__ float sc[16];
  for (int o = 32; o; o >>= 1) v += __shfl_down(v, o);
  __syncthreads();
  if ((threadIdx.x & 63) == 0) sc[threadIdx.x >> 6] = v;
  __syncthreads();
  if (threadIdx.x == 0) {
    float r = 0.f;
    for (int i = 0; i < 16; ++i) r += sc[i];
    sc[0] = r;
  }
  __syncthreads();
  return sc[0];
}

__global__ __launch_bounds__(1024) void k_final2(const float* __restrict__ partials,
    const float* __restrict__ Gpart, float* __restrict__ out) {
  __shared__ float comb[30];
  int t = threadIdx.x;
  if (t < 30) {
    float a = 0.f;
    for (int b = 0; b < 32; ++b) a += partials[b * 30 + t];
    comb[t] = a;
  }
  float val = 0.f;
  if (t < 729) {
    int k = t / 27, l = t - k * 27;
    int gidx = (k + 1) * 32 + (l + 1);
    for (int b = 0; b < 64; ++b) val += Gpart[(size_t)b * 1024 + gidx];
  }
  __syncthreads();
  float F2 = block_sum_1024(val * val);
  float F = sqrtf(F2);
  bool diag = (t < 729) && (t % 28 == 0);
  float gg = (t < 729) ? (val / F - (diag ? (1.f / sqrtf(27.f)) : 0.f)) : 0.f;
  float O2 = block_sum_1024(gg * gg);
  float ortho = sqrtf(O2);
  if (t == 0) {
    float sumDeg = comb[0], T1 = comb[1], maxsum = comb[2];
    float norm = 0.5f * sumDeg;
    float vv = 0.f;
    for (int k = 0; k < KCL; ++k) vv += comb[3 + k] * comb[3 + k];
    float c = 0.05f / (2.f * norm);
    float sm = -(T1 - c * vv) / (2.f * norm);
    float cl = -maxsum / (float)NTOT;
    out[0] = sm + cl + ortho;
    out[1] = sm;
  }
}

extern "C" void kernel_launch(void* const* d_in, const int* in_sizes, int n_in,
                              void* d_out, int out_size, void* d_ws, size_t ws_size,
                              hipStream_t stream) {
  const float* x        = (const float*)d_in[0];
  const float* clusters = (const float*)d_in[1];
  const float* alpha    = (const float*)d_in[2];
  float* out = (float*)d_out;
  float* ws  = (float*)d_ws;

  // workspace layout (float offsets)
  const size_t OFF_MBF  = 0;                                    // bf16 [8192][512]
  const size_t OFF_NCLB = (size_t)NTOT * CDIM / 2;              // bf16 [32][512]
  const size_t OFF_ST   = OFF_NCLB + (size_t)32 * CDIM / 2;     // f32 sT [27][8192]
  const size_t OFF_SXB  = OFF_ST + (size_t)NTOT * KCL;          // bf16 sxT [32][8192]
  const size_t OFF_MAXV = OFF_SXB + (size_t)32 * NTOT / 2;
  const size_t OFF_SQ   = OFF_MAXV + NTOT;                      // f32 [4][8192]
  const size_t OFF_R    = OFF_SQ + (size_t)4 * NTOT;            // Rpart: 16*28*8192 f32
  const size_t OFF_GP   = OFF_R + (size_t)16 * 28 * NTOT;       // Gpart: 64*1024 f32
  const size_t OFF_PART = OFF_GP + (size_t)64 * 1024;           // 32*30 partials

  unsigned short* mbf  = (unsigned short*)(ws + OFF_MBF);
  unsigned short* nclb = (unsigned short*)(ws + OFF_NCLB);
  unsigned short* sxbf = (unsigned short*)(ws + OFF_SXB);

  // no memsets needed: nclb rows 27-31 / sxbf rows 28-31 feed only output
  // columns >= 28, which are never read. Contents are replay-invariant.
  k_merged2<<<539, 256, 0, stream>>>(x, clusters, mbf, nclb, ws + OFF_SQ);
  k_inner2<<<256, 256, 0, stream>>>(mbf, nclb, alpha, ws + OFF_SQ,
                                    ws + OFF_ST, ws + OFF_MAXV, out + 2, sxbf);
  k_fused<<<dim3(64, 16), 256, 0, stream>>>(mbf, sxbf, ws + OFF_R);
  k_tail<<<96, 256, 0, stream>>>(sxbf, ws + OFF_R, ws + OFF_ST, ws + OFF_MAXV,
                                 ws + OFF_GP, ws + OFF_PART);
  k_final2<<<1, 1024, 0, stream>>>(ws + OFF_PART, ws + OFF_GP, out);
}